// Round 1
// baseline (1236.577 us; speedup 1.0000x reference)
//
#include <hip/hip_runtime.h>
#include <hip/hip_fp16.h>

// Problem: B=4, S=2048, D=1024, fp32 in/out.
// q = x@wq^T; kv = x@wv^T; scores = q @ reshape(kv,[D,S]) / 32;
// sm = softmax(scores, axis=-1); sm = tril(sm) (post-softmax, no renorm);
// out = sm @ kv.
//
// ws layout (needs ~100.7 MB):
//   q  fp32 [4*2048*1024]           @ byte 0
//   kv fp32 [4*2048*1024]           @ byte 33554432
//   Sc fp16 [4*2048*2048]           @ byte 67108864  (scores, then P in place)

#define TM 128
#define TN 128
#define TK 16

// ---------------- GEMM 1: C[m,n] = sum_k A[m,k] * W[n,k] (A:[8192,1024], W:[1024,1024])
__global__ __launch_bounds__(256) void gemm_xwT(const float* __restrict__ A,
                                                const float* __restrict__ W,
                                                float* __restrict__ C) {
  const int K = 1024, N = 1024;
  __shared__ float As[TK][TM + 4];
  __shared__ float Bs[TK][TN + 4];
  const int m0 = blockIdx.x * TM;
  const int n0 = blockIdx.y * TN;
  const int tid = threadIdx.x;
  const int tx = tid & 15, ty = tid >> 4;
  float acc[8][8] = {};
  for (int k0 = 0; k0 < K; k0 += TK) {
#pragma unroll
    for (int i = 0; i < 2; ++i) {
      int lin = tid + i * 256;      // 0..511 float4 slots per tile
      int m = lin >> 2;             // 0..127
      int k4 = (lin & 3) << 2;      // 0,4,8,12
      float4 va = *(const float4*)(A + (size_t)(m0 + m) * K + k0 + k4);
      As[k4 + 0][m] = va.x; As[k4 + 1][m] = va.y;
      As[k4 + 2][m] = va.z; As[k4 + 3][m] = va.w;
      float4 vb = *(const float4*)(W + (size_t)(n0 + m) * K + k0 + k4);
      Bs[k4 + 0][m] = vb.x; Bs[k4 + 1][m] = vb.y;
      Bs[k4 + 2][m] = vb.z; Bs[k4 + 3][m] = vb.w;
    }
    __syncthreads();
#pragma unroll
    for (int k = 0; k < TK; ++k) {
      float a[8], bb[8];
#pragma unroll
      for (int i = 0; i < 8; ++i) a[i] = As[k][ty * 8 + i];
#pragma unroll
      for (int j = 0; j < 8; ++j) bb[j] = Bs[k][tx * 8 + j];
#pragma unroll
      for (int i = 0; i < 8; ++i)
#pragma unroll
        for (int j = 0; j < 8; ++j)
          acc[i][j] = fmaf(a[i], bb[j], acc[i][j]);
    }
    __syncthreads();
  }
#pragma unroll
  for (int i = 0; i < 8; ++i) {
    float* cp = C + (size_t)(m0 + ty * 8 + i) * N + n0 + tx * 8;
    *(float4*)cp       = make_float4(acc[i][0], acc[i][1], acc[i][2], acc[i][3]);
    *(float4*)(cp + 4) = make_float4(acc[i][4], acc[i][5], acc[i][6], acc[i][7]);
  }
}

// ---------------- GEMM 2 (per-b): Sc = (Q[b] @ KVview[b]) / 32, fp16 out.
// KVview[b] is kv[b]'s buffer reinterpreted row-major [1024][2048] (the raw reshape).
__global__ __launch_bounds__(256) void gemm_scores(const float* __restrict__ Q,
                                                   const float* __restrict__ KV,
                                                   __half* __restrict__ Sc) {
  const int K = 1024, N = 2048;
  __shared__ float As[TK][TM + 4];
  __shared__ float Bs[TK][TN + 4];
  const int b = blockIdx.z;
  const float* A  = Q  + (size_t)b * 2048 * 1024;
  const float* Bm = KV + (size_t)b * 2048 * 1024;  // viewed [1024][2048]
  __half* C = Sc + (size_t)b * 2048 * 2048;
  const int m0 = blockIdx.x * TM;
  const int n0 = blockIdx.y * TN;
  const int tid = threadIdx.x;
  const int tx = tid & 15, ty = tid >> 4;
  float acc[8][8] = {};
  for (int k0 = 0; k0 < K; k0 += TK) {
#pragma unroll
    for (int i = 0; i < 2; ++i) {
      int lin = tid + i * 256;
      int m = lin >> 2;
      int k4 = (lin & 3) << 2;
      float4 va = *(const float4*)(A + (size_t)(m0 + m) * K + k0 + k4);
      As[k4 + 0][m] = va.x; As[k4 + 1][m] = va.y;
      As[k4 + 2][m] = va.z; As[k4 + 3][m] = va.w;
      int k  = lin >> 5;            // 0..15
      int n4 = (lin & 31) << 2;     // 0..124
      float4 vb = *(const float4*)(Bm + (size_t)(k0 + k) * N + n0 + n4);
      *(float4*)&Bs[k][n4] = vb;
    }
    __syncthreads();
#pragma unroll
    for (int k = 0; k < TK; ++k) {
      float a[8], bb[8];
#pragma unroll
      for (int i = 0; i < 8; ++i) a[i] = As[k][ty * 8 + i];
#pragma unroll
      for (int j = 0; j < 8; ++j) bb[j] = Bs[k][tx * 8 + j];
#pragma unroll
      for (int i = 0; i < 8; ++i)
#pragma unroll
        for (int j = 0; j < 8; ++j)
          acc[i][j] = fmaf(a[i], bb[j], acc[i][j]);
    }
    __syncthreads();
  }
#pragma unroll
  for (int i = 0; i < 8; ++i) {
    __half ho[8];
#pragma unroll
    for (int j = 0; j < 8; ++j) ho[j] = __float2half(acc[i][j] * 0.03125f);
    *(uint4*)(C + (size_t)(m0 + ty * 8 + i) * N + n0 + tx * 8) = *(const uint4*)ho;
  }
}

// ---------------- softmax over full row (2048), then zero t>s, in place (fp16).
__global__ __launch_bounds__(256) void softmax_mask(__half* __restrict__ S) {
  const int row = blockIdx.x;       // 0..8191 ; buffer is contiguous [8192][2048]
  const int s = row & 2047;
  __half* p = S + (size_t)row * 2048;
  const int tid = threadIdx.x;
  uint4 u = *((const uint4*)p + tid);   // halves tid*8 .. tid*8+7
  const __half* h = (const __half*)&u;
  float v[8];
#pragma unroll
  for (int j = 0; j < 8; ++j) v[j] = __half2float(h[j]);
  float mx = v[0];
#pragma unroll
  for (int j = 1; j < 8; ++j) mx = fmaxf(mx, v[j]);
#pragma unroll
  for (int off = 32; off > 0; off >>= 1) mx = fmaxf(mx, __shfl_xor(mx, off));
  __shared__ float red[8];
  const int wave = tid >> 6, lane = tid & 63;
  if (lane == 0) red[wave] = mx;
  __syncthreads();
  mx = fmaxf(fmaxf(red[0], red[1]), fmaxf(red[2], red[3]));
  float se = 0.f;
#pragma unroll
  for (int j = 0; j < 8; ++j) se += __expf(v[j] - mx);
#pragma unroll
  for (int off = 32; off > 0; off >>= 1) se += __shfl_xor(se, off);
  if (lane == 0) red[4 + wave] = se;
  __syncthreads();
  const float inv = 1.f / (red[4] + red[5] + red[6] + red[7]);
  __half ho[8];
#pragma unroll
  for (int j = 0; j < 8; ++j) {
    int t = tid * 8 + j;
    ho[j] = __float2half((t <= s) ? __expf(v[j] - mx) * inv : 0.f);
  }
  *((uint4*)p + tid) = *(const uint4*)ho;
}

// ---------------- GEMM 3 (per-b): Out = P(fp16) @ KV (fp32), fp32 out.
__global__ __launch_bounds__(256) void gemm_pv(const __half* __restrict__ P,
                                               const float* __restrict__ KV,
                                               float* __restrict__ Out) {
  const int K = 2048, N = 1024;
  __shared__ float As[TK][TM + 4];
  __shared__ float Bs[TK][TN + 4];
  const int b = blockIdx.z;
  const __half* A = P + (size_t)b * 2048 * 2048;
  const float* Bm = KV + (size_t)b * 2048 * 1024;
  float* C = Out + (size_t)b * 2048 * 1024;
  const int m0 = blockIdx.x * TM;
  const int n0 = blockIdx.y * TN;
  const int tid = threadIdx.x;
  const int tx = tid & 15, ty = tid >> 4;
  float acc[8][8] = {};
  for (int k0 = 0; k0 < K; k0 += TK) {
    {
      int m  = tid >> 1;            // 0..127
      int kh = (tid & 1) << 3;      // 0 or 8
      uint4 u = *(const uint4*)(A + (size_t)(m0 + m) * K + k0 + kh);
      const __half* hh = (const __half*)&u;
#pragma unroll
      for (int j = 0; j < 8; ++j) As[kh + j][m] = __half2float(hh[j]);
    }
#pragma unroll
    for (int i = 0; i < 2; ++i) {
      int lin = tid + i * 256;
      int k  = lin >> 5;
      int n4 = (lin & 31) << 2;
      float4 vb = *(const float4*)(Bm + (size_t)(k0 + k) * N + n0 + n4);
      *(float4*)&Bs[k][n4] = vb;
    }
    __syncthreads();
#pragma unroll
    for (int k = 0; k < TK; ++k) {
      float a[8], bb[8];
#pragma unroll
      for (int i = 0; i < 8; ++i) a[i] = As[k][ty * 8 + i];
#pragma unroll
      for (int j = 0; j < 8; ++j) bb[j] = Bs[k][tx * 8 + j];
#pragma unroll
      for (int i = 0; i < 8; ++i)
#pragma unroll
        for (int j = 0; j < 8; ++j)
          acc[i][j] = fmaf(a[i], bb[j], acc[i][j]);
    }
    __syncthreads();
  }
#pragma unroll
  for (int i = 0; i < 8; ++i) {
    float* cp = C + (size_t)(m0 + ty * 8 + i) * N + n0 + tx * 8;
    *(float4*)cp       = make_float4(acc[i][0], acc[i][1], acc[i][2], acc[i][3]);
    *(float4*)(cp + 4) = make_float4(acc[i][4], acc[i][5], acc[i][6], acc[i][7]);
  }
}

extern "C" void kernel_launch(void* const* d_in, const int* in_sizes, int n_in,
                              void* d_out, int out_size, void* d_ws, size_t ws_size,
                              hipStream_t stream) {
  const float* x  = (const float*)d_in[0];
  const float* wq = (const float*)d_in[1];
  const float* wv = (const float*)d_in[2];
  float* out = (float*)d_out;

  float* q  = (float*)d_ws;                       // 8M floats
  float* kv = q + (size_t)8 * 1024 * 1024;        // 8M floats
  __half* Sc = (__half*)(kv + (size_t)8 * 1024 * 1024);  // 16M halves

  dim3 blk(256);
  // q = x@wq^T ; kv = x@wv^T   (M=8192, N=1024, K=1024)
  gemm_xwT<<<dim3(64, 8), blk, 0, stream>>>(x, wq, q);
  gemm_xwT<<<dim3(64, 8), blk, 0, stream>>>(x, wv, kv);
  // scores (fp16) = q @ kv_view / 32   (per b: M=2048, N=2048, K=1024)
  gemm_scores<<<dim3(16, 16, 4), blk, 0, stream>>>(q, kv, Sc);
  // softmax + post-softmax causal mask, in place
  softmax_mask<<<dim3(8192), blk, 0, stream>>>(Sc);
  // out = P @ kv   (per b: M=2048, N=1024, K=2048)
  gemm_pv<<<dim3(16, 8, 4), blk, 0, stream>>>(Sc, kv, out);
}

// Round 2
// 214.114 us; speedup vs baseline: 5.7753x; 5.7753x over previous
//
#include <hip/hip_runtime.h>

// B=4, S=2048, D=1024, fp32 in/out.
// q = x@wq^T; kv = x@wv^T; Sc = q @ reshape(kv,[D,S]) / 32 (raw reshape!);
// P = softmax(Sc, full row); P = tril(P) (post-softmax, no renorm); out = P@kv.
//
// All GEMMs run as fp16 MFMA (mfma_f32_16x16x32_f16, f32 accum), m97
// structure: 128x128 tile, BK=32, 4 waves, global_load_lds staging.
//
// ws (96 MB known-safe; upgraded layout if >=128MB):
//   Sc   fp16 [bc*2048*2048]  @ 0            (bc = 2 or 4)
//   qh   fp16 [8192*1024]     @ Sc end
//   kvh  fp16 [8192*1024]     @ +16MB
//   kvvT fp16 [4*2048*1024]   @ +32MB   (B^T for scores)
//   kvT  fp16 [4*1024*2048]   @ +48MB   (B^T for pv)
//   (xh/wqh/wvh live transiently inside the Sc region)

typedef __attribute__((ext_vector_type(8))) _Float16 f16x8;
typedef __attribute__((ext_vector_type(4))) _Float16 f16x4;
typedef __attribute__((ext_vector_type(4))) float f32x4;

__device__ __forceinline__ void glds16(const void* g, void* l) {
  __builtin_amdgcn_global_load_lds((const __attribute__((address_space(1))) void*)g,
                                   (__attribute__((address_space(3))) void*)l, 16, 0, 0);
}

// ---------------- fp32 -> fp16 convert (4 elems/thread)
__global__ __launch_bounds__(256) void cvt_f16(const float* __restrict__ in,
                                               _Float16* __restrict__ out, int n4) {
  int i = blockIdx.x * 256 + threadIdx.x;
  if (i < n4) {
    float4 v = ((const float4*)in)[i];
    f16x4 o = {(_Float16)v.x, (_Float16)v.y, (_Float16)v.z, (_Float16)v.w};
    ((f16x4*)out)[i] = o;
  }
}

// ---------------- tiled fp16 transpose: out[c][r] = in[r][c], per blockIdx.z slab
__global__ __launch_bounds__(256) void transpose_f16(const _Float16* __restrict__ in,
                                                     _Float16* __restrict__ out,
                                                     int R, int C) {
  __shared__ _Float16 T[64][65];
  const size_t off = (size_t)blockIdx.z * R * C;
  const _Float16* I = in + off;
  _Float16* O = out + off;
  const int c0 = blockIdx.x * 64, r0 = blockIdx.y * 64;
  const int t = threadIdx.x;
#pragma unroll
  for (int i = 0; i < 2; ++i) {
    int lin = (t + i * 256) * 8;
    int r = lin >> 6, c = lin & 63;
    uint4 v = *(const uint4*)(I + (size_t)(r0 + r) * C + c0 + c);
    const _Float16* h = (const _Float16*)&v;
#pragma unroll
    for (int j = 0; j < 8; ++j) T[r][c + j] = h[j];
  }
  __syncthreads();
#pragma unroll
  for (int i = 0; i < 2; ++i) {
    int lin = (t + i * 256) * 8;
    int cc = lin >> 6, rr = lin & 63;
    _Float16 o[8];
#pragma unroll
    for (int j = 0; j < 8; ++j) o[j] = T[rr + j][cc];
    *(uint4*)(O + (size_t)(c0 + cc) * R + r0 + rr) = *(const uint4*)o;
  }
}

// ---------------- MFMA GEMM: C = scale * (A @ BT^T)
// A [M][K] f16 row-major, BT [N][K] f16 row-major, C [M][ldc] OUT_T.
// M%128==0, N%128==0, K%32==0. Per-z strides in elements.
template <typename OUT_T>
__global__ __launch_bounds__(256) void gemm_tn(const _Float16* __restrict__ A,
                                               const _Float16* __restrict__ BT,
                                               OUT_T* __restrict__ C,
                                               int M, int N, int K, int ldc,
                                               long sA, long sB, long sC, float scale) {
  __shared__ _Float16 As[128 * 32];
  __shared__ _Float16 Bs[128 * 32];
  A += (size_t)blockIdx.z * sA;
  BT += (size_t)blockIdx.z * sB;
  C += (size_t)blockIdx.z * sC;
  const int m0 = blockIdx.x * 128;
  const int n0 = blockIdx.y * 128;
  const int lane = threadIdx.x & 63;
  const int wave = threadIdx.x >> 6;
  const int wr = (wave >> 1) * 64, wc = (wave & 1) * 64;
  const int fr = lane & 15;   // row-in-16 of A frag / col-in-16 of B frag
  const int fc = lane >> 4;   // k-chunk 0..3

  f32x4 acc[4][4] = {};
  const int srow = (lane >> 2);        // staging row-in-chunk
  const int skc = (lane & 3) * 8;      // staging k offset

  for (int k0 = 0; k0 < K; k0 += 32) {
#pragma unroll
    for (int i = 0; i < 2; ++i) {
      int ch = wave * 2 + i;           // 0..7, 16 rows each
      int row = ch * 16 + srow;
      glds16(A + (size_t)(m0 + row) * K + k0 + skc, &As[ch * 512]);
      glds16(BT + (size_t)(n0 + row) * K + k0 + skc, &Bs[ch * 512]);
    }
    __syncthreads();
    f16x8 af[4], bf[4];
#pragma unroll
    for (int m = 0; m < 4; ++m)
      af[m] = *(const f16x8*)&As[(wr + m * 16 + fr) * 32 + fc * 8];
#pragma unroll
    for (int n = 0; n < 4; ++n)
      bf[n] = *(const f16x8*)&Bs[(wc + n * 16 + fr) * 32 + fc * 8];
#pragma unroll
    for (int m = 0; m < 4; ++m)
#pragma unroll
      for (int n = 0; n < 4; ++n)
        acc[m][n] = __builtin_amdgcn_mfma_f32_16x16x32_f16(af[m], bf[n], acc[m][n], 0, 0, 0);
    __syncthreads();
  }
#pragma unroll
  for (int m = 0; m < 4; ++m)
#pragma unroll
    for (int n = 0; n < 4; ++n) {
      const int row = m0 + wr + m * 16 + fc * 4;
      const int col = n0 + wc + n * 16 + fr;
#pragma unroll
      for (int r = 0; r < 4; ++r)
        C[(size_t)(row + r) * ldc + col] = (OUT_T)(acc[m][n][r] * scale);
    }
}

// ---------------- softmax over full 2048 row, then zero t>s, in place (fp16)
__global__ __launch_bounds__(256) void softmax_mask(_Float16* __restrict__ S) {
  const int row = blockIdx.x;          // contiguous [nrows][2048]; s = row % 2048
  const int s = row & 2047;
  _Float16* p = S + (size_t)row * 2048;
  const int tid = threadIdx.x;
  uint4 u = ((const uint4*)p)[tid];
  const _Float16* h = (const _Float16*)&u;
  float v[8];
#pragma unroll
  for (int j = 0; j < 8; ++j) v[j] = (float)h[j];
  float mx = v[0];
#pragma unroll
  for (int j = 1; j < 8; ++j) mx = fmaxf(mx, v[j]);
#pragma unroll
  for (int off = 32; off > 0; off >>= 1) mx = fmaxf(mx, __shfl_xor(mx, off));
  __shared__ float red[8];
  const int wave = tid >> 6, lane = tid & 63;
  if (lane == 0) red[wave] = mx;
  __syncthreads();
  mx = fmaxf(fmaxf(red[0], red[1]), fmaxf(red[2], red[3]));
  float se = 0.f;
#pragma unroll
  for (int j = 0; j < 8; ++j) se += __expf(v[j] - mx);
#pragma unroll
  for (int off = 32; off > 0; off >>= 1) se += __shfl_xor(se, off);
  if (lane == 0) red[4 + wave] = se;
  __syncthreads();
  const float inv = 1.f / (red[4] + red[5] + red[6] + red[7]);
  _Float16 o[8];
#pragma unroll
  for (int j = 0; j < 8; ++j) {
    int t = tid * 8 + j;
    o[j] = (_Float16)((t <= s) ? __expf(v[j] - mx) * inv : 0.f);
  }
  ((uint4*)p)[tid] = *(const uint4*)o;
}

extern "C" void kernel_launch(void* const* d_in, const int* in_sizes, int n_in,
                              void* d_out, int out_size, void* d_ws, size_t ws_size,
                              hipStream_t stream) {
  const float* x = (const float*)d_in[0];
  const float* wq = (const float*)d_in[1];
  const float* wv = (const float*)d_in[2];
  float* out = (float*)d_out;
  char* ws = (char*)d_ws;

  const size_t MB = 1024 * 1024;
  const int bc = (ws_size >= 128 * MB) ? 4 : 2;        // batches per Sc chunk
  const size_t scBytes = (size_t)bc * 2048 * 2048 * 2; // 32 or 64 MB
  const long PB = 2048 * 1024;                         // per-b q/kv elems
  const long SB = (long)2048 * 2048;                   // per-b score elems

  _Float16* Sc = (_Float16*)ws;
  _Float16* qh = (_Float16*)(ws + scBytes);
  _Float16* kvh = (_Float16*)(ws + scBytes + 16 * MB);
  _Float16* kvvT = (_Float16*)(ws + scBytes + 32 * MB);
  _Float16* kvT = (_Float16*)(ws + scBytes + 48 * MB);
  _Float16* xh = (_Float16*)ws;                 // transient, inside Sc region
  _Float16* wqh = (_Float16*)(ws + 16 * MB);
  _Float16* wvh = (_Float16*)(ws + 18 * MB);

  // 1) fp32 -> fp16
  cvt_f16<<<8192, 256, 0, stream>>>(x, xh, 2 * 1024 * 1024);
  cvt_f16<<<1024, 256, 0, stream>>>(wq, wqh, 256 * 1024);
  cvt_f16<<<1024, 256, 0, stream>>>(wv, wvh, 256 * 1024);

  // 2) qh = xh@wqh^T ; kvh = xh@wvh^T   (M=8192, N=1024, K=1024)
  gemm_tn<_Float16><<<dim3(64, 8, 1), 256, 0, stream>>>(xh, wqh, qh, 8192, 1024, 1024, 1024, 0, 0, 0, 1.0f);
  gemm_tn<_Float16><<<dim3(64, 8, 1), 256, 0, stream>>>(xh, wvh, kvh, 8192, 1024, 1024, 1024, 0, 0, 0, 1.0f);

  // 3) B^T materialization:
  //    kvvT[b][n][k] = kv_flat[b][k*2048+n]  (transpose of the [1024][2048] view)
  transpose_f16<<<dim3(32, 16, 4), 256, 0, stream>>>(kvh, kvvT, 1024, 2048);
  //    kvT[b][d][t] = kv[b][t][d]
  transpose_f16<<<dim3(16, 32, 4), 256, 0, stream>>>(kvh, kvT, 2048, 1024);

  // 4) per batch-chunk: scores -> softmax+mask -> PV
  for (int b0 = 0; b0 < 4; b0 += bc) {
    gemm_tn<_Float16><<<dim3(16, 16, bc), 256, 0, stream>>>(
        qh + (size_t)b0 * PB, kvvT + (size_t)b0 * PB, Sc,
        2048, 2048, 1024, 2048, PB, PB, SB, 0.03125f);
    softmax_mask<<<bc * 2048, 256, 0, stream>>>(Sc);
    gemm_tn<float><<<dim3(16, 8, bc), 256, 0, stream>>>(
        Sc, kvT + (size_t)b0 * PB, out + (size_t)b0 * PB,
        2048, 1024, 2048, 1024, SB, PB, PB, 1.0f);
  }
}

// Round 3
// 168.676 us; speedup vs baseline: 7.3311x; 1.2694x over previous
//
#include <hip/hip_runtime.h>

// B=4, S=2048, D=1024, fp32 in/out.
// q = x@wq^T; kv = x@wv^T; Sc = q @ reshape(kv,[D,S]) / 32 (raw reshape!);
// P = softmax(Sc, full row); P = tril(P) (post-softmax, no renorm); out = P@kv.
//
// GEMM engines:
//  - gemm8p: 256x256 tile, BK=64, 8 waves, 8-phase schedule w/ counted vmcnt,
//    XOR-swizzled LDS (T2+T3+T4+T5).  Used for q/kv (fused) and scores.
//  - gemm_tn: proven 128x128 2-phase kernel, used for PV with causal K-skip.

typedef __attribute__((ext_vector_type(8))) _Float16 f16x8;
typedef __attribute__((ext_vector_type(4))) _Float16 f16x4;
typedef __attribute__((ext_vector_type(4))) float f32x4;

__device__ __forceinline__ void glds16(const void* g, void* l) {
  __builtin_amdgcn_global_load_lds((const __attribute__((address_space(1))) void*)g,
                                   (__attribute__((address_space(3))) void*)l, 16, 0, 0);
}
#define BAR() __builtin_amdgcn_s_barrier()
#define LGKM0() do { asm volatile("s_waitcnt lgkmcnt(0)" ::: "memory"); \
                     __builtin_amdgcn_sched_barrier(0); } while (0)
#define VM2() asm volatile("s_waitcnt vmcnt(2)" ::: "memory")

// ---------------- fp32 -> fp16 convert
__global__ __launch_bounds__(256) void cvt_f16(const float* __restrict__ in,
                                               _Float16* __restrict__ out, int n4) {
  int i = blockIdx.x * 256 + threadIdx.x;
  if (i < n4) {
    float4 v = ((const float4*)in)[i];
    f16x4 o = {(_Float16)v.x, (_Float16)v.y, (_Float16)v.z, (_Float16)v.w};
    ((f16x4*)out)[i] = o;
  }
}

// ---------------- tiled fp16 transpose: out[c][r] = in[r][c], per blockIdx.z slab
__global__ __launch_bounds__(256) void transpose_f16(const _Float16* __restrict__ in,
                                                     _Float16* __restrict__ out,
                                                     int R, int C) {
  __shared__ _Float16 T[64][65];
  const size_t off = (size_t)blockIdx.z * R * C;
  const _Float16* I = in + off;
  _Float16* O = out + off;
  const int c0 = blockIdx.x * 64, r0 = blockIdx.y * 64;
  const int t = threadIdx.x;
#pragma unroll
  for (int i = 0; i < 2; ++i) {
    int lin = (t + i * 256) * 8;
    int r = lin >> 6, c = lin & 63;
    uint4 v = *(const uint4*)(I + (size_t)(r0 + r) * C + c0 + c);
    const _Float16* h = (const _Float16*)&v;
#pragma unroll
    for (int j = 0; j < 8; ++j) T[r][c + j] = h[j];
  }
  __syncthreads();
#pragma unroll
  for (int i = 0; i < 2; ++i) {
    int lin = (t + i * 256) * 8;
    int cc = lin >> 6, rr = lin & 63;
    _Float16 o[8];
#pragma unroll
    for (int j = 0; j < 8; ++j) o[j] = T[rr + j][cc];
    *(uint4*)(O + (size_t)(c0 + cc) * R + r0 + rr) = *(const uint4*)o;
  }
}

// ================= 8-phase 256^2 MFMA GEMM: C = scale * (A @ BT^T) =================
// A [M][K], BT [N][K] fp16 row-major; C [M][ldc] OUT_T. M,N %256==0, K %128==0.
// LDS halves (fp16 elems): buf d at d*32768; A0 +0, A1 +8192, B0 +16384, B1 +24576.
// Swizzle: LDS[row][byte] holds global[row][byte ^ ((row&7)<<4)] (both sides XOR).
template <typename OUT_T>
__global__ __launch_bounds__(512, 2) void gemm8p(const _Float16* __restrict__ A,
                                                 const _Float16* __restrict__ BT,
                                                 OUT_T* __restrict__ C,
                                                 int K, int ldc,
                                                 long sA, long sB, long sC, float scale) {
  extern __shared__ char smem[];
  _Float16* lds = (_Float16*)smem;
  A += (size_t)blockIdx.z * sA;
  BT += (size_t)blockIdx.z * sB;
  C += (size_t)blockIdx.z * sC;
  const int m0 = blockIdx.x << 8, n0 = blockIdx.y << 8;
  const int tid = threadIdx.x, lane = tid & 63, wave = tid >> 6;
  const int wm = wave >> 2, wn = wave & 3;       // 2 x 4 wave grid
  const int lr = lane & 15, lk = lane >> 4, xr = lane & 7;
  const int nkt = K >> 6;                        // 64-wide K tiles (even count)
  const int A0 = 0, A1 = 8192, B0 = 16384, B1 = 24576, BUF = 32768;
  const int baseA = wm ? A1 : A0;                // wave reads only its A-half
  const int baseB = B0 + ((wn >> 1) << 13);      // and its B-half
  const int bRow = (wn & 1) << 6;                // 64-row offset inside B-half
  const int srow = lane >> 3;                    // staging row 0..7
  const int scolB = ((lane & 7) << 4) ^ (srow << 4);  // pre-swizzled src byte-in-row

  f32x4 acc[8][4] = {};
  f16x8 fa[4][2], fb[2][2];

#define STAGE(bufsel, halfsel, G, hrow0, kt) do {                                   \
    const _Float16* _g = (G) + (size_t)((hrow0) + wave * 16 + srow) * K + ((kt) << 6); \
    glds16((const char*)_g + scolB, (char*)&lds[(bufsel) * BUF + (halfsel) + wave * 1024]);        \
    glds16((const char*)(_g + (size_t)8 * K) + scolB,                                \
           (char*)&lds[(bufsel) * BUF + (halfsel) + wave * 1024 + 512]);             \
  } while (0)
#define RDA(buf, mf, ks) (*(const f16x8*)&lds[(buf) * BUF + baseA + ((mf) * 16 + lr) * 64 + \
                                              ((((ks) * 4 + lk) ^ xr) << 3)])
#define RDB(buf, nf, ks) (*(const f16x8*)&lds[(buf) * BUF + baseB + (bRow + (nf) * 16 + lr) * 64 + \
                                              ((((ks) * 4 + lk) ^ xr) << 3)])
#define MM(i, j, ks0, ks1) do {                                                      \
    acc[i][j] = __builtin_amdgcn_mfma_f32_16x16x32_f16(fa[ks0][0], fb[ks1][0], acc[i][j], 0, 0, 0); \
    acc[i][j] = __builtin_amdgcn_mfma_f32_16x16x32_f16(fa[ks0][1], fb[ks1][1], acc[i][j], 0, 0, 0); \
  } while (0)

  // prologue: tile0 -> buf0 (4 halves), tile1.A0 -> buf1; wait tile0 landed.
  STAGE(0, A0, A, m0, 0);
  STAGE(0, A1, A, m0 + 128, 0);
  STAGE(0, B0, BT, n0, 0);
  STAGE(0, B1, BT, n0 + 128, 0);
  STAGE(1, A0, A, m0, 1);
  VM2();
  BAR();

  for (int it = 0; it < (nkt >> 1); ++it) {
    const int t = it << 1;
    const int t2 = (t + 2 < nkt) ? t + 2 : 0;   // clamp keeps vmcnt arithmetic uniform
    const int t3 = (t + 3 < nkt) ? t + 3 : 0;
    // ---- ph1: buf0 (mh=0, nh=0); stage buf1.A1, buf1.B0 (tile t+1)
#pragma unroll
    for (int i = 0; i < 4; ++i) { fa[i][0] = RDA(0, i, 0); fa[i][1] = RDA(0, i, 1); }
#pragma unroll
    for (int j = 0; j < 2; ++j) { fb[j][0] = RDB(0, j, 0); fb[j][1] = RDB(0, j, 1); }
    STAGE(1, A1, A, m0 + 128, t + 1);
    STAGE(1, B0, BT, n0, t + 1);
    BAR(); LGKM0();
    __builtin_amdgcn_s_setprio(1);
#pragma unroll
    for (int i = 0; i < 4; ++i)
#pragma unroll
      for (int j = 0; j < 2; ++j) MM(i, j, i, j);
    __builtin_amdgcn_s_setprio(0);
    BAR();
    // ---- ph2: (mh=0, nh=1), reuse fa; stage buf1.B1 (t+1)
#pragma unroll
    for (int j = 0; j < 2; ++j) { fb[j][0] = RDB(0, 2 + j, 0); fb[j][1] = RDB(0, 2 + j, 1); }
    STAGE(1, B1, BT, n0 + 128, t + 1);
    BAR(); LGKM0();
    __builtin_amdgcn_s_setprio(1);
#pragma unroll
    for (int i = 0; i < 4; ++i)
#pragma unroll
      for (int j = 0; j < 2; ++j) MM(i, 2 + j, i, j);
    __builtin_amdgcn_s_setprio(0);
    BAR();
    // ---- ph3: (mh=1, nh=1), reuse fb; no stage
#pragma unroll
    for (int i = 0; i < 4; ++i) { fa[i][0] = RDA(0, 4 + i, 0); fa[i][1] = RDA(0, 4 + i, 1); }
    BAR(); LGKM0();
    __builtin_amdgcn_s_setprio(1);
#pragma unroll
    for (int i = 0; i < 4; ++i)
#pragma unroll
      for (int j = 0; j < 2; ++j) MM(4 + i, 2 + j, i, j);
    __builtin_amdgcn_s_setprio(0);
    BAR();
    // ---- ph4: (mh=1, nh=0), reuse fa; stage buf0.A0 (t+2); vmcnt(2)
#pragma unroll
    for (int j = 0; j < 2; ++j) { fb[j][0] = RDB(0, j, 0); fb[j][1] = RDB(0, j, 1); }
    STAGE(0, A0, A, m0, t2);
    VM2();
    BAR(); LGKM0();
    __builtin_amdgcn_s_setprio(1);
#pragma unroll
    for (int i = 0; i < 4; ++i)
#pragma unroll
      for (int j = 0; j < 2; ++j) MM(4 + i, j, i, j);
    __builtin_amdgcn_s_setprio(0);
    BAR();
    // ---- ph5: buf1 (mh=0, nh=0); stage buf0.A1, buf0.B0 (t+2)
#pragma unroll
    for (int i = 0; i < 4; ++i) { fa[i][0] = RDA(1, i, 0); fa[i][1] = RDA(1, i, 1); }
#pragma unroll
    for (int j = 0; j < 2; ++j) { fb[j][0] = RDB(1, j, 0); fb[j][1] = RDB(1, j, 1); }
    STAGE(0, A1, A, m0 + 128, t2);
    STAGE(0, B0, BT, n0, t2);
    BAR(); LGKM0();
    __builtin_amdgcn_s_setprio(1);
#pragma unroll
    for (int i = 0; i < 4; ++i)
#pragma unroll
      for (int j = 0; j < 2; ++j) MM(i, j, i, j);
    __builtin_amdgcn_s_setprio(0);
    BAR();
    // ---- ph6: (mh=0, nh=1); stage buf0.B1 (t+2)
#pragma unroll
    for (int j = 0; j < 2; ++j) { fb[j][0] = RDB(1, 2 + j, 0); fb[j][1] = RDB(1, 2 + j, 1); }
    STAGE(0, B1, BT, n0 + 128, t2);
    BAR(); LGKM0();
    __builtin_amdgcn_s_setprio(1);
#pragma unroll
    for (int i = 0; i < 4; ++i)
#pragma unroll
      for (int j = 0; j < 2; ++j) MM(i, 2 + j, i, j);
    __builtin_amdgcn_s_setprio(0);
    BAR();
    // ---- ph7: (mh=1, nh=1); no stage
#pragma unroll
    for (int i = 0; i < 4; ++i) { fa[i][0] = RDA(1, 4 + i, 0); fa[i][1] = RDA(1, 4 + i, 1); }
    BAR(); LGKM0();
    __builtin_amdgcn_s_setprio(1);
#pragma unroll
    for (int i = 0; i < 4; ++i)
#pragma unroll
      for (int j = 0; j < 2; ++j) MM(4 + i, 2 + j, i, j);
    __builtin_amdgcn_s_setprio(0);
    BAR();
    // ---- ph8: (mh=1, nh=0); stage buf1.A0 (t+3); vmcnt(2)
#pragma unroll
    for (int j = 0; j < 2; ++j) { fb[j][0] = RDB(1, j, 0); fb[j][1] = RDB(1, j, 1); }
    STAGE(1, A0, A, m0, t3);
    VM2();
    BAR(); LGKM0();
    __builtin_amdgcn_s_setprio(1);
#pragma unroll
    for (int i = 0; i < 4; ++i)
#pragma unroll
      for (int j = 0; j < 2; ++j) MM(4 + i, j, i, j);
    __builtin_amdgcn_s_setprio(0);
    BAR();
  }

  // epilogue
#pragma unroll
  for (int mf = 0; mf < 8; ++mf)
#pragma unroll
    for (int nf = 0; nf < 4; ++nf) {
      const int row = m0 + wm * 128 + mf * 16 + lk * 4;
      const int col = n0 + wn * 64 + nf * 16 + lr;
#pragma unroll
      for (int r = 0; r < 4; ++r)
        C[(size_t)(row + r) * ldc + col] = (OUT_T)(acc[mf][nf][r] * scale);
    }
#undef STAGE
#undef RDA
#undef RDB
#undef MM
}

// ================= 2-phase 128^2 GEMM (PV, with causal K-skip) =================
template <typename OUT_T, bool CAUSAL>
__global__ __launch_bounds__(256) void gemm_tn(const _Float16* __restrict__ A,
                                               const _Float16* __restrict__ BT,
                                               OUT_T* __restrict__ C,
                                               int M, int N, int K, int ldc,
                                               long sA, long sB, long sC, float scale) {
  __shared__ _Float16 As[128 * 32];
  __shared__ _Float16 Bs[128 * 32];
  A += (size_t)blockIdx.z * sA;
  BT += (size_t)blockIdx.z * sB;
  C += (size_t)blockIdx.z * sC;
  const int m0 = blockIdx.x * 128;
  const int n0 = blockIdx.y * 128;
  const int lane = threadIdx.x & 63;
  const int wave = threadIdx.x >> 6;
  const int wr = (wave >> 1) * 64, wc = (wave & 1) * 64;
  const int fr = lane & 15;
  const int fc = lane >> 4;
  f32x4 acc[4][4] = {};
  const int srow = (lane >> 2);
  const int skc = (lane & 3) * 8;
  const int Kend = CAUSAL ? ((m0 + 128 < K) ? m0 + 128 : K) : K;

  for (int k0 = 0; k0 < Kend; k0 += 32) {
#pragma unroll
    for (int i = 0; i < 2; ++i) {
      int ch = wave * 2 + i;
      int row = ch * 16 + srow;
      glds16(A + (size_t)(m0 + row) * K + k0 + skc, &As[ch * 512]);
      glds16(BT + (size_t)(n0 + row) * K + k0 + skc, &Bs[ch * 512]);
    }
    __syncthreads();
    f16x8 af[4], bf[4];
#pragma unroll
    for (int m = 0; m < 4; ++m)
      af[m] = *(const f16x8*)&As[(wr + m * 16 + fr) * 32 + fc * 8];
#pragma unroll
    for (int n = 0; n < 4; ++n)
      bf[n] = *(const f16x8*)&Bs[(wc + n * 16 + fr) * 32 + fc * 8];
#pragma unroll
    for (int m = 0; m < 4; ++m)
#pragma unroll
      for (int n = 0; n < 4; ++n)
        acc[m][n] = __builtin_amdgcn_mfma_f32_16x16x32_f16(af[m], bf[n], acc[m][n], 0, 0, 0);
    __syncthreads();
  }
#pragma unroll
  for (int m = 0; m < 4; ++m)
#pragma unroll
    for (int n = 0; n < 4; ++n) {
      const int row = m0 + wr + m * 16 + fc * 4;
      const int col = n0 + wc + n * 16 + fr;
#pragma unroll
      for (int r = 0; r < 4; ++r)
        C[(size_t)(row + r) * ldc + col] = (OUT_T)(acc[m][n][r] * scale);
    }
}

// ---------------- softmax over full 2048 row, then zero t>s, in place (fp16)
__global__ __launch_bounds__(256) void softmax_mask(_Float16* __restrict__ S) {
  const int row = blockIdx.x;
  const int s = row & 2047;
  _Float16* p = S + (size_t)row * 2048;
  const int tid = threadIdx.x;
  uint4 u = ((const uint4*)p)[tid];
  const _Float16* h = (const _Float16*)&u;
  float v[8];
#pragma unroll
  for (int j = 0; j < 8; ++j) v[j] = (float)h[j];
  float mx = v[0];
#pragma unroll
  for (int j = 1; j < 8; ++j) mx = fmaxf(mx, v[j]);
#pragma unroll
  for (int off = 32; off > 0; off >>= 1) mx = fmaxf(mx, __shfl_xor(mx, off));
  __shared__ float red[8];
  const int wave = tid >> 6, lane = tid & 63;
  if (lane == 0) red[wave] = mx;
  __syncthreads();
  mx = fmaxf(fmaxf(red[0], red[1]), fmaxf(red[2], red[3]));
  float se = 0.f;
#pragma unroll
  for (int j = 0; j < 8; ++j) se += __expf(v[j] - mx);
#pragma unroll
  for (int off = 32; off > 0; off >>= 1) se += __shfl_xor(se, off);
  if (lane == 0) red[4 + wave] = se;
  __syncthreads();
  const float inv = 1.f / (red[4] + red[5] + red[6] + red[7]);
  _Float16 o[8];
#pragma unroll
  for (int j = 0; j < 8; ++j) {
    int t = tid * 8 + j;
    o[j] = (_Float16)((t <= s) ? __expf(v[j] - mx) * inv : 0.f);
  }
  ((uint4*)p)[tid] = *(const uint4*)o;
}

extern "C" void kernel_launch(void* const* d_in, const int* in_sizes, int n_in,
                              void* d_out, int out_size, void* d_ws, size_t ws_size,
                              hipStream_t stream) {
  const float* x = (const float*)d_in[0];
  const float* wq = (const float*)d_in[1];
  const float* wv = (const float*)d_in[2];
  float* out = (float*)d_out;
  char* ws = (char*)d_ws;

  const size_t MB = 1024 * 1024;
  const int bc = (ws_size >= 128 * MB) ? 4 : 2;
  const size_t scBytes = (size_t)bc * 2048 * 2048 * 2;
  const long PB = 2048 * 1024;
  const long SB = (long)2048 * 2048;

  _Float16* Sc = (_Float16*)ws;
  _Float16* qh = (_Float16*)(ws + scBytes);
  _Float16* kvh = (_Float16*)(ws + scBytes + 16 * MB);
  _Float16* kvvT = (_Float16*)(ws + scBytes + 32 * MB);
  _Float16* kvT = (_Float16*)(ws + scBytes + 48 * MB);
  _Float16* xh = (_Float16*)ws;     // transient (inside Sc region)
  _Float16* wqh = (_Float16*)(ws + 16 * MB);
  _Float16* wvh = (_Float16*)(ws + 18 * MB);

  // 1) fp32 -> fp16
  cvt_f16<<<8192, 256, 0, stream>>>(x, xh, 2 * 1024 * 1024);
  cvt_f16<<<1024, 256, 0, stream>>>(wq, wqh, 256 * 1024);
  cvt_f16<<<1024, 256, 0, stream>>>(wv, wvh, 256 * 1024);

  // 2) fused qh = xh@wqh^T, kvh = xh@wvh^T  (z selects weight/output)
  gemm8p<_Float16><<<dim3(32, 4, 2), 512, 131072, stream>>>(
      xh, wqh, qh, 1024, 1024, 0, (long)(wvh - wqh), (long)(kvh - qh), 1.0f);

  // 3) B^T materialization
  transpose_f16<<<dim3(32, 16, 4), 256, 0, stream>>>(kvh, kvvT, 1024, 2048);
  transpose_f16<<<dim3(16, 32, 4), 256, 0, stream>>>(kvh, kvT, 2048, 1024);

  // 4) per batch-chunk: scores -> softmax+mask -> PV (causal K-skip)
  for (int b0 = 0; b0 < 4; b0 += bc) {
    gemm8p<_Float16><<<dim3(8, 8, bc), 512, 131072, stream>>>(
        qh + (size_t)b0 * PB, kvvT + (size_t)b0 * PB, Sc,
        1024, 2048, PB, PB, SB, 0.03125f);
    softmax_mask<<<bc * 2048, 256, 0, stream>>>(Sc);
    gemm_tn<float, true><<<dim3(16, 8, bc), 256, 0, stream>>>(
        Sc, kvT + (size_t)b0 * PB, out + (size_t)b0 * PB,
        2048, 1024, 2048, 1024, SB, PB, PB, 1.0f);
  }
}

// Round 4
// 162.779 us; speedup vs baseline: 7.5967x; 1.0362x over previous
//
#include <hip/hip_runtime.h>

// B=4, S=2048, D=1024, fp32 in/out.
// q = x@wq^T; kv = x@wv^T; Sc = q @ reshape(kv,[D,S]) / 32 (raw reshape!);
// P = softmax(Sc, full row); P = tril(P) (post-softmax, no renorm); out = P@kv.
//
// Engines:
//  - gemm8p: 256x256, BK=64, 8 waves, 8-phase counted-vmcnt, XOR-swizzled LDS.
//    Used for fused q/kv and for scores.
//  - gemm_pv_bal: balanced causal PV. 64-row m-strip pairs (p, 31-p) so every
//    block does identical K work (2112 steps); 2-phase 64x128 tile, 4 waves.

typedef __attribute__((ext_vector_type(8))) _Float16 f16x8;
typedef __attribute__((ext_vector_type(4))) _Float16 f16x4;
typedef __attribute__((ext_vector_type(4))) float f32x4;

__device__ __forceinline__ void glds16(const void* g, void* l) {
  __builtin_amdgcn_global_load_lds((const __attribute__((address_space(1))) void*)g,
                                   (__attribute__((address_space(3))) void*)l, 16, 0, 0);
}
#define BAR() __builtin_amdgcn_s_barrier()
#define LGKM0() do { asm volatile("s_waitcnt lgkmcnt(0)" ::: "memory"); \
                     __builtin_amdgcn_sched_barrier(0); } while (0)
#define VM2() asm volatile("s_waitcnt vmcnt(2)" ::: "memory")

// ---------------- fp32 -> fp16 convert
__global__ __launch_bounds__(256) void cvt_f16(const float* __restrict__ in,
                                               _Float16* __restrict__ out, int n4) {
  int i = blockIdx.x * 256 + threadIdx.x;
  if (i < n4) {
    float4 v = ((const float4*)in)[i];
    f16x4 o = {(_Float16)v.x, (_Float16)v.y, (_Float16)v.z, (_Float16)v.w};
    ((f16x4*)out)[i] = o;
  }
}

// ---------------- tiled fp16 transpose: out[c][r] = in[r][c], per blockIdx.z slab
__global__ __launch_bounds__(256) void transpose_f16(const _Float16* __restrict__ in,
                                                     _Float16* __restrict__ out,
                                                     int R, int C) {
  __shared__ _Float16 T[64][65];
  const size_t off = (size_t)blockIdx.z * R * C;
  const _Float16* I = in + off;
  _Float16* O = out + off;
  const int c0 = blockIdx.x * 64, r0 = blockIdx.y * 64;
  const int t = threadIdx.x;
#pragma unroll
  for (int i = 0; i < 2; ++i) {
    int lin = (t + i * 256) * 8;
    int r = lin >> 6, c = lin & 63;
    uint4 v = *(const uint4*)(I + (size_t)(r0 + r) * C + c0 + c);
    const _Float16* h = (const _Float16*)&v;
#pragma unroll
    for (int j = 0; j < 8; ++j) T[r][c + j] = h[j];
  }
  __syncthreads();
#pragma unroll
  for (int i = 0; i < 2; ++i) {
    int lin = (t + i * 256) * 8;
    int cc = lin >> 6, rr = lin & 63;
    _Float16 o[8];
#pragma unroll
    for (int j = 0; j < 8; ++j) o[j] = T[rr + j][cc];
    *(uint4*)(O + (size_t)(c0 + cc) * R + r0 + rr) = *(const uint4*)o;
  }
}

// ================= 8-phase 256^2 MFMA GEMM: C = scale * (A @ BT^T) =================
template <typename OUT_T>
__global__ __launch_bounds__(512, 2) void gemm8p(const _Float16* __restrict__ A,
                                                 const _Float16* __restrict__ BT,
                                                 OUT_T* __restrict__ C,
                                                 int K, int ldc,
                                                 long sA, long sB, long sC, float scale) {
  extern __shared__ char smem[];
  _Float16* lds = (_Float16*)smem;
  A += (size_t)blockIdx.z * sA;
  BT += (size_t)blockIdx.z * sB;
  C += (size_t)blockIdx.z * sC;
  const int m0 = blockIdx.x << 8, n0 = blockIdx.y << 8;
  const int tid = threadIdx.x, lane = tid & 63, wave = tid >> 6;
  const int wm = wave >> 2, wn = wave & 3;
  const int lr = lane & 15, lk = lane >> 4, xr = lane & 7;
  const int nkt = K >> 6;
  const int A0 = 0, A1 = 8192, B0 = 16384, B1 = 24576, BUF = 32768;
  const int baseA = wm ? A1 : A0;
  const int baseB = B0 + ((wn >> 1) << 13);
  const int bRow = (wn & 1) << 6;
  const int srow = lane >> 3;
  const int scolB = ((lane & 7) << 4) ^ (srow << 4);

  f32x4 acc[8][4] = {};
  f16x8 fa[4][2], fb[2][2];

#define STAGE(bufsel, halfsel, G, hrow0, kt) do {                                   \
    const _Float16* _g = (G) + (size_t)((hrow0) + wave * 16 + srow) * K + ((kt) << 6); \
    glds16((const char*)_g + scolB, (char*)&lds[(bufsel) * BUF + (halfsel) + wave * 1024]);        \
    glds16((const char*)(_g + (size_t)8 * K) + scolB,                                \
           (char*)&lds[(bufsel) * BUF + (halfsel) + wave * 1024 + 512]);             \
  } while (0)
#define RDA(buf, mf, ks) (*(const f16x8*)&lds[(buf) * BUF + baseA + ((mf) * 16 + lr) * 64 + \
                                              ((((ks) * 4 + lk) ^ xr) << 3)])
#define RDB(buf, nf, ks) (*(const f16x8*)&lds[(buf) * BUF + baseB + (bRow + (nf) * 16 + lr) * 64 + \
                                              ((((ks) * 4 + lk) ^ xr) << 3)])
#define MM(i, j, ks0, ks1) do {                                                      \
    acc[i][j] = __builtin_amdgcn_mfma_f32_16x16x32_f16(fa[ks0][0], fb[ks1][0], acc[i][j], 0, 0, 0); \
    acc[i][j] = __builtin_amdgcn_mfma_f32_16x16x32_f16(fa[ks0][1], fb[ks1][1], acc[i][j], 0, 0, 0); \
  } while (0)

  STAGE(0, A0, A, m0, 0);
  STAGE(0, A1, A, m0 + 128, 0);
  STAGE(0, B0, BT, n0, 0);
  STAGE(0, B1, BT, n0 + 128, 0);
  STAGE(1, A0, A, m0, 1);
  VM2();
  BAR();

  for (int it = 0; it < (nkt >> 1); ++it) {
    const int t = it << 1;
    const int t2 = (t + 2 < nkt) ? t + 2 : 0;
    const int t3 = (t + 3 < nkt) ? t + 3 : 0;
    // ph1
#pragma unroll
    for (int i = 0; i < 4; ++i) { fa[i][0] = RDA(0, i, 0); fa[i][1] = RDA(0, i, 1); }
#pragma unroll
    for (int j = 0; j < 2; ++j) { fb[j][0] = RDB(0, j, 0); fb[j][1] = RDB(0, j, 1); }
    STAGE(1, A1, A, m0 + 128, t + 1);
    STAGE(1, B0, BT, n0, t + 1);
    BAR(); LGKM0();
    __builtin_amdgcn_s_setprio(1);
#pragma unroll
    for (int i = 0; i < 4; ++i)
#pragma unroll
      for (int j = 0; j < 2; ++j) MM(i, j, i, j);
    __builtin_amdgcn_s_setprio(0);
    BAR();
    // ph2
#pragma unroll
    for (int j = 0; j < 2; ++j) { fb[j][0] = RDB(0, 2 + j, 0); fb[j][1] = RDB(0, 2 + j, 1); }
    STAGE(1, B1, BT, n0 + 128, t + 1);
    BAR(); LGKM0();
    __builtin_amdgcn_s_setprio(1);
#pragma unroll
    for (int i = 0; i < 4; ++i)
#pragma unroll
      for (int j = 0; j < 2; ++j) MM(i, 2 + j, i, j);
    __builtin_amdgcn_s_setprio(0);
    BAR();
    // ph3
#pragma unroll
    for (int i = 0; i < 4; ++i) { fa[i][0] = RDA(0, 4 + i, 0); fa[i][1] = RDA(0, 4 + i, 1); }
    BAR(); LGKM0();
    __builtin_amdgcn_s_setprio(1);
#pragma unroll
    for (int i = 0; i < 4; ++i)
#pragma unroll
      for (int j = 0; j < 2; ++j) MM(4 + i, 2 + j, i, j);
    __builtin_amdgcn_s_setprio(0);
    BAR();
    // ph4
#pragma unroll
    for (int j = 0; j < 2; ++j) { fb[j][0] = RDB(0, j, 0); fb[j][1] = RDB(0, j, 1); }
    STAGE(0, A0, A, m0, t2);
    VM2();
    BAR(); LGKM0();
    __builtin_amdgcn_s_setprio(1);
#pragma unroll
    for (int i = 0; i < 4; ++i)
#pragma unroll
      for (int j = 0; j < 2; ++j) MM(4 + i, j, i, j);
    __builtin_amdgcn_s_setprio(0);
    BAR();
    // ph5
#pragma unroll
    for (int i = 0; i < 4; ++i) { fa[i][0] = RDA(1, i, 0); fa[i][1] = RDA(1, i, 1); }
#pragma unroll
    for (int j = 0; j < 2; ++j) { fb[j][0] = RDB(1, j, 0); fb[j][1] = RDB(1, j, 1); }
    STAGE(0, A1, A, m0 + 128, t2);
    STAGE(0, B0, BT, n0, t2);
    BAR(); LGKM0();
    __builtin_amdgcn_s_setprio(1);
#pragma unroll
    for (int i = 0; i < 4; ++i)
#pragma unroll
      for (int j = 0; j < 2; ++j) MM(i, j, i, j);
    __builtin_amdgcn_s_setprio(0);
    BAR();
    // ph6
#pragma unroll
    for (int j = 0; j < 2; ++j) { fb[j][0] = RDB(1, 2 + j, 0); fb[j][1] = RDB(1, 2 + j, 1); }
    STAGE(0, B1, BT, n0 + 128, t2);
    BAR(); LGKM0();
    __builtin_amdgcn_s_setprio(1);
#pragma unroll
    for (int i = 0; i < 4; ++i)
#pragma unroll
      for (int j = 0; j < 2; ++j) MM(i, 2 + j, i, j);
    __builtin_amdgcn_s_setprio(0);
    BAR();
    // ph7
#pragma unroll
    for (int i = 0; i < 4; ++i) { fa[i][0] = RDA(1, 4 + i, 0); fa[i][1] = RDA(1, 4 + i, 1); }
    BAR(); LGKM0();
    __builtin_amdgcn_s_setprio(1);
#pragma unroll
    for (int i = 0; i < 4; ++i)
#pragma unroll
      for (int j = 0; j < 2; ++j) MM(4 + i, 2 + j, i, j);
    __builtin_amdgcn_s_setprio(0);
    BAR();
    // ph8
#pragma unroll
    for (int j = 0; j < 2; ++j) { fb[j][0] = RDB(1, j, 0); fb[j][1] = RDB(1, j, 1); }
    STAGE(1, A0, A, m0, t3);
    VM2();
    BAR(); LGKM0();
    __builtin_amdgcn_s_setprio(1);
#pragma unroll
    for (int i = 0; i < 4; ++i)
#pragma unroll
      for (int j = 0; j < 2; ++j) MM(4 + i, j, i, j);
    __builtin_amdgcn_s_setprio(0);
    BAR();
  }

#pragma unroll
  for (int mf = 0; mf < 8; ++mf)
#pragma unroll
    for (int nf = 0; nf < 4; ++nf) {
      const int row = m0 + wm * 128 + mf * 16 + lk * 4;
      const int col = n0 + wn * 64 + nf * 16 + lr;
#pragma unroll
      for (int r = 0; r < 4; ++r)
        C[(size_t)(row + r) * ldc + col] = (OUT_T)(acc[mf][nf][r] * scale);
    }
#undef STAGE
#undef RDA
#undef RDB
#undef MM
}

// ================= balanced causal PV: Out = P @ KVT^T =================
// Per batch: M=2048 (32 strips of 64 rows), N=1024, K=2048, Kend(strip)=m0+64.
// Block (p, ny, b): strips {p, 31-p} sequentially -> uniform 2112 K-steps/block.
// Tile 64x128, 4 waves (per-wave 64x32), 2-phase staging.
__global__ __launch_bounds__(256) void gemm_pv_bal(const _Float16* __restrict__ P,
                                                   const _Float16* __restrict__ KVT,
                                                   float* __restrict__ Out,
                                                   long sA, long sB, long sC) {
  __shared__ _Float16 As[64 * 32];
  __shared__ _Float16 Bs[128 * 32];
  P += (size_t)blockIdx.z * sA;
  KVT += (size_t)blockIdx.z * sB;
  Out += (size_t)blockIdx.z * sC;
  const int n0 = blockIdx.y * 128;
  const int lane = threadIdx.x & 63, wave = threadIdx.x >> 6;
  const int fr = lane & 15, fc = lane >> 4;
  const int srow = lane >> 2, skc = (lane & 3) * 8;

#pragma unroll
  for (int half = 0; half < 2; ++half) {
    const int strip = half ? (31 - blockIdx.x) : blockIdx.x;
    const int m0 = strip * 64;
    const int Kend = m0 + 64;
    f32x4 acc[4][2] = {};
    for (int k0 = 0; k0 < Kend; k0 += 32) {
      // A: rows m0..m0+63 (wave w: rows w*16..+15)
      glds16(P + (size_t)(m0 + wave * 16 + srow) * 2048 + k0 + skc, &As[wave * 512]);
      // B: rows n0..n0+127 (wave w: rows w*32..+31, two issues)
      glds16(KVT + (size_t)(n0 + wave * 32 + srow) * 2048 + k0 + skc, &Bs[wave * 1024]);
      glds16(KVT + (size_t)(n0 + wave * 32 + 16 + srow) * 2048 + k0 + skc, &Bs[wave * 1024 + 512]);
      __syncthreads();
      f16x8 af[4], bf[2];
#pragma unroll
      for (int m = 0; m < 4; ++m)
        af[m] = *(const f16x8*)&As[(m * 16 + fr) * 32 + fc * 8];
#pragma unroll
      for (int n = 0; n < 2; ++n)
        bf[n] = *(const f16x8*)&Bs[(wave * 32 + n * 16 + fr) * 32 + fc * 8];
#pragma unroll
      for (int m = 0; m < 4; ++m)
#pragma unroll
        for (int n = 0; n < 2; ++n)
          acc[m][n] = __builtin_amdgcn_mfma_f32_16x16x32_f16(af[m], bf[n], acc[m][n], 0, 0, 0);
      __syncthreads();
    }
#pragma unroll
    for (int m = 0; m < 4; ++m)
#pragma unroll
      for (int n = 0; n < 2; ++n) {
        const int row = m0 + m * 16 + fc * 4;
        const int col = n0 + wave * 32 + n * 16 + fr;
#pragma unroll
        for (int r = 0; r < 4; ++r)
          Out[(size_t)(row + r) * 1024 + col] = acc[m][n][r];
      }
  }
}

// ---------------- softmax over full 2048 row, zero t>s; skip chunks PV never reads
__global__ __launch_bounds__(256) void softmax_mask(_Float16* __restrict__ S) {
  const int row = blockIdx.x;
  const int s = row & 2047;
  _Float16* p = S + (size_t)row * 2048;
  const int tid = threadIdx.x;
  uint4 u = ((const uint4*)p)[tid];
  const _Float16* h = (const _Float16*)&u;
  float v[8];
#pragma unroll
  for (int j = 0; j < 8; ++j) v[j] = (float)h[j];
  float mx = v[0];
#pragma unroll
  for (int j = 1; j < 8; ++j) mx = fmaxf(mx, v[j]);
#pragma unroll
  for (int off = 32; off > 0; off >>= 1) mx = fmaxf(mx, __shfl_xor(mx, off));
  __shared__ float red[8];
  const int wave = tid >> 6, lane = tid & 63;
  if (lane == 0) red[wave] = mx;
  __syncthreads();
  mx = fmaxf(fmaxf(red[0], red[1]), fmaxf(red[2], red[3]));
  float se = 0.f;
#pragma unroll
  for (int j = 0; j < 8; ++j) se += __expf(v[j] - mx);
#pragma unroll
  for (int off = 32; off > 0; off >>= 1) se += __shfl_xor(se, off);
  if (lane == 0) red[4 + wave] = se;
  __syncthreads();
  const float inv = 1.f / (red[4] + red[5] + red[6] + red[7]);
  // PV reads row s only for t < (s & ~63) + 64 (its 64-row strip's Kend).
  const int lim = (s & ~63) + 64;
  if (tid * 8 < lim) {
    _Float16 o[8];
#pragma unroll
    for (int j = 0; j < 8; ++j) {
      int t = tid * 8 + j;
      o[j] = (_Float16)((t <= s) ? __expf(v[j] - mx) * inv : 0.f);
    }
    ((uint4*)p)[tid] = *(const uint4*)o;
  }
}

extern "C" void kernel_launch(void* const* d_in, const int* in_sizes, int n_in,
                              void* d_out, int out_size, void* d_ws, size_t ws_size,
                              hipStream_t stream) {
  const float* x = (const float*)d_in[0];
  const float* wq = (const float*)d_in[1];
  const float* wv = (const float*)d_in[2];
  float* out = (float*)d_out;
  char* ws = (char*)d_ws;

  const size_t MB = 1024 * 1024;
  const int bc = (ws_size >= 128 * MB) ? 4 : 2;
  const size_t scBytes = (size_t)bc * 2048 * 2048 * 2;
  const long PB = 2048 * 1024;
  const long SB = (long)2048 * 2048;

  _Float16* Sc = (_Float16*)ws;
  _Float16* qh = (_Float16*)(ws + scBytes);
  _Float16* kvh = (_Float16*)(ws + scBytes + 16 * MB);
  _Float16* kvvT = (_Float16*)(ws + scBytes + 32 * MB);
  _Float16* kvT = (_Float16*)(ws + scBytes + 48 * MB);
  _Float16* xh = (_Float16*)ws;
  _Float16* wqh = (_Float16*)(ws + 16 * MB);
  _Float16* wvh = (_Float16*)(ws + 18 * MB);

  // 1) fp32 -> fp16
  cvt_f16<<<8192, 256, 0, stream>>>(x, xh, 2 * 1024 * 1024);
  cvt_f16<<<1024, 256, 0, stream>>>(wq, wqh, 256 * 1024);
  cvt_f16<<<1024, 256, 0, stream>>>(wv, wvh, 256 * 1024);

  // 2) fused qh = xh@wqh^T, kvh = xh@wvh^T
  gemm8p<_Float16><<<dim3(32, 4, 2), 512, 131072, stream>>>(
      xh, wqh, qh, 1024, 1024, 0, (long)(wvh - wqh), (long)(kvh - qh), 1.0f);

  // 3) B^T materialization
  transpose_f16<<<dim3(32, 16, 4), 256, 0, stream>>>(kvh, kvvT, 1024, 2048);
  transpose_f16<<<dim3(16, 32, 4), 256, 0, stream>>>(kvh, kvT, 2048, 1024);

  // 4) per batch-chunk: scores -> softmax+mask -> balanced causal PV
  for (int b0 = 0; b0 < 4; b0 += bc) {
    gemm8p<_Float16><<<dim3(8, 8, bc), 512, 131072, stream>>>(
        qh + (size_t)b0 * PB, kvvT + (size_t)b0 * PB, Sc,
        1024, 2048, PB, PB, SB, 0.03125f);
    softmax_mask<<<bc * 2048, 256, 0, stream>>>(Sc);
    gemm_pv_bal<<<dim3(16, 8, bc), 256, 0, stream>>>(
        Sc, kvT + (size_t)b0 * PB, out + (size_t)b0 * PB, SB, PB, PB);
  }
}

// Round 5
// 159.261 us; speedup vs baseline: 7.7645x; 1.0221x over previous
//
#include <hip/hip_runtime.h>

// B=4, S=2048, D=1024, fp32 in/out.
// q = x@wq^T; kv = x@wv^T; Sc = q @ reshape(kv,[D,S]) / 32 (raw reshape!);
// P = softmax(Sc, full row); P = tril(P) (post-softmax, no renorm); out = P@kv.
//
// Engines:
//  - gemm8p: 256x256, BK=64, 8 waves, 8-phase counted-vmcnt, XOR-swizzled LDS.
//  - gemm_pv_bal: balanced causal PV. 32-row strip pairs (p,63-p) -> uniform
//    2080 K-cols/block; 32x128 tile, 4 waves; XCD-grouped block remap;
//    (row>>1)&3 XOR slot swizzle both sides (2-way banks).
// ws (96 MiB, proven): Sc[bc*8MiB] | qh 16 | kvh 16 | kvvT 16 | kvT 16.

typedef __attribute__((ext_vector_type(8))) _Float16 f16x8;
typedef __attribute__((ext_vector_type(4))) _Float16 f16x4;
typedef __attribute__((ext_vector_type(4))) float f32x4;

__device__ __forceinline__ void glds16(const void* g, void* l) {
  __builtin_amdgcn_global_load_lds((const __attribute__((address_space(1))) void*)g,
                                   (__attribute__((address_space(3))) void*)l, 16, 0, 0);
}
#define BAR() __builtin_amdgcn_s_barrier()
#define LGKM0() do { asm volatile("s_waitcnt lgkmcnt(0)" ::: "memory"); \
                     __builtin_amdgcn_sched_barrier(0); } while (0)
#define VM2() asm volatile("s_waitcnt vmcnt(2)" ::: "memory")

// ---------------- fp32 -> fp16 convert
__global__ __launch_bounds__(256) void cvt_f16(const float* __restrict__ in,
                                               _Float16* __restrict__ out, int n4) {
  int i = blockIdx.x * 256 + threadIdx.x;
  if (i < n4) {
    float4 v = ((const float4*)in)[i];
    f16x4 o = {(_Float16)v.x, (_Float16)v.y, (_Float16)v.z, (_Float16)v.w};
    ((f16x4*)out)[i] = o;
  }
}

// ---------------- tiled fp16 transpose: out[c][r] = in[r][c], per blockIdx.z slab
__global__ __launch_bounds__(256) void transpose_f16(const _Float16* __restrict__ in,
                                                     _Float16* __restrict__ out,
                                                     int R, int C) {
  __shared__ _Float16 T[64][65];
  const size_t off = (size_t)blockIdx.z * R * C;
  const _Float16* I = in + off;
  _Float16* O = out + off;
  const int c0 = blockIdx.x * 64, r0 = blockIdx.y * 64;
  const int t = threadIdx.x;
#pragma unroll
  for (int i = 0; i < 2; ++i) {
    int lin = (t + i * 256) * 8;
    int r = lin >> 6, c = lin & 63;
    uint4 v = *(const uint4*)(I + (size_t)(r0 + r) * C + c0 + c);
    const _Float16* h = (const _Float16*)&v;
#pragma unroll
    for (int j = 0; j < 8; ++j) T[r][c + j] = h[j];
  }
  __syncthreads();
#pragma unroll
  for (int i = 0; i < 2; ++i) {
    int lin = (t + i * 256) * 8;
    int cc = lin >> 6, rr = lin & 63;
    _Float16 o[8];
#pragma unroll
    for (int j = 0; j < 8; ++j) o[j] = T[rr + j][cc];
    *(uint4*)(O + (size_t)(c0 + cc) * R + r0 + rr) = *(const uint4*)o;
  }
}

// ================= 8-phase 256^2 MFMA GEMM: C = scale * (A @ BT^T) =================
template <typename OUT_T>
__global__ __launch_bounds__(512, 2) void gemm8p(const _Float16* __restrict__ A,
                                                 const _Float16* __restrict__ BT,
                                                 OUT_T* __restrict__ C,
                                                 int K, int ldc,
                                                 long sA, long sB, long sC, float scale) {
  extern __shared__ char smem[];
  _Float16* lds = (_Float16*)smem;
  A += (size_t)blockIdx.z * sA;
  BT += (size_t)blockIdx.z * sB;
  C += (size_t)blockIdx.z * sC;
  const int m0 = blockIdx.x << 8, n0 = blockIdx.y << 8;
  const int tid = threadIdx.x, lane = tid & 63, wave = tid >> 6;
  const int wm = wave >> 2, wn = wave & 3;
  const int lr = lane & 15, lk = lane >> 4, xr = lane & 7;
  const int nkt = K >> 6;
  const int A0 = 0, A1 = 8192, B0 = 16384, B1 = 24576, BUF = 32768;
  const int baseA = wm ? A1 : A0;
  const int baseB = B0 + ((wn >> 1) << 13);
  const int bRow = (wn & 1) << 6;
  const int srow = lane >> 3;
  const int scolB = ((lane & 7) << 4) ^ (srow << 4);

  f32x4 acc[8][4] = {};
  f16x8 fa[4][2], fb[2][2];

#define STAGE(bufsel, halfsel, G, hrow0, kt) do {                                   \
    const _Float16* _g = (G) + (size_t)((hrow0) + wave * 16 + srow) * K + ((kt) << 6); \
    glds16((const char*)_g + scolB, (char*)&lds[(bufsel) * BUF + (halfsel) + wave * 1024]);        \
    glds16((const char*)(_g + (size_t)8 * K) + scolB,                                \
           (char*)&lds[(bufsel) * BUF + (halfsel) + wave * 1024 + 512]);             \
  } while (0)
#define RDA(buf, mf, ks) (*(const f16x8*)&lds[(buf) * BUF + baseA + ((mf) * 16 + lr) * 64 + \
                                              ((((ks) * 4 + lk) ^ xr) << 3)])
#define RDB(buf, nf, ks) (*(const f16x8*)&lds[(buf) * BUF + baseB + (bRow + (nf) * 16 + lr) * 64 + \
                                              ((((ks) * 4 + lk) ^ xr) << 3)])
#define MM(i, j, ks0, ks1) do {                                                      \
    acc[i][j] = __builtin_amdgcn_mfma_f32_16x16x32_f16(fa[ks0][0], fb[ks1][0], acc[i][j], 0, 0, 0); \
    acc[i][j] = __builtin_amdgcn_mfma_f32_16x16x32_f16(fa[ks0][1], fb[ks1][1], acc[i][j], 0, 0, 0); \
  } while (0)

  STAGE(0, A0, A, m0, 0);
  STAGE(0, A1, A, m0 + 128, 0);
  STAGE(0, B0, BT, n0, 0);
  STAGE(0, B1, BT, n0 + 128, 0);
  STAGE(1, A0, A, m0, 1);
  VM2();
  BAR();

  for (int it = 0; it < (nkt >> 1); ++it) {
    const int t = it << 1;
    const int t2 = (t + 2 < nkt) ? t + 2 : 0;
    const int t3 = (t + 3 < nkt) ? t + 3 : 0;
    // ph1
#pragma unroll
    for (int i = 0; i < 4; ++i) { fa[i][0] = RDA(0, i, 0); fa[i][1] = RDA(0, i, 1); }
#pragma unroll
    for (int j = 0; j < 2; ++j) { fb[j][0] = RDB(0, j, 0); fb[j][1] = RDB(0, j, 1); }
    STAGE(1, A1, A, m0 + 128, t + 1);
    STAGE(1, B0, BT, n0, t + 1);
    BAR(); LGKM0();
    __builtin_amdgcn_s_setprio(1);
#pragma unroll
    for (int i = 0; i < 4; ++i)
#pragma unroll
      for (int j = 0; j < 2; ++j) MM(i, j, i, j);
    __builtin_amdgcn_s_setprio(0);
    BAR();
    // ph2
#pragma unroll
    for (int j = 0; j < 2; ++j) { fb[j][0] = RDB(0, 2 + j, 0); fb[j][1] = RDB(0, 2 + j, 1); }
    STAGE(1, B1, BT, n0 + 128, t + 1);
    BAR(); LGKM0();
    __builtin_amdgcn_s_setprio(1);
#pragma unroll
    for (int i = 0; i < 4; ++i)
#pragma unroll
      for (int j = 0; j < 2; ++j) MM(i, 2 + j, i, j);
    __builtin_amdgcn_s_setprio(0);
    BAR();
    // ph3
#pragma unroll
    for (int i = 0; i < 4; ++i) { fa[i][0] = RDA(0, 4 + i, 0); fa[i][1] = RDA(0, 4 + i, 1); }
    BAR(); LGKM0();
    __builtin_amdgcn_s_setprio(1);
#pragma unroll
    for (int i = 0; i < 4; ++i)
#pragma unroll
      for (int j = 0; j < 2; ++j) MM(4 + i, 2 + j, i, j);
    __builtin_amdgcn_s_setprio(0);
    BAR();
    // ph4
#pragma unroll
    for (int j = 0; j < 2; ++j) { fb[j][0] = RDB(0, j, 0); fb[j][1] = RDB(0, j, 1); }
    STAGE(0, A0, A, m0, t2);
    VM2();
    BAR(); LGKM0();
    __builtin_amdgcn_s_setprio(1);
#pragma unroll
    for (int i = 0; i < 4; ++i)
#pragma unroll
      for (int j = 0; j < 2; ++j) MM(4 + i, j, i, j);
    __builtin_amdgcn_s_setprio(0);
    BAR();
    // ph5
#pragma unroll
    for (int i = 0; i < 4; ++i) { fa[i][0] = RDA(1, i, 0); fa[i][1] = RDA(1, i, 1); }
#pragma unroll
    for (int j = 0; j < 2; ++j) { fb[j][0] = RDB(1, j, 0); fb[j][1] = RDB(1, j, 1); }
    STAGE(0, A1, A, m0 + 128, t2);
    STAGE(0, B0, BT, n0, t2);
    BAR(); LGKM0();
    __builtin_amdgcn_s_setprio(1);
#pragma unroll
    for (int i = 0; i < 4; ++i)
#pragma unroll
      for (int j = 0; j < 2; ++j) MM(i, j, i, j);
    __builtin_amdgcn_s_setprio(0);
    BAR();
    // ph6
#pragma unroll
    for (int j = 0; j < 2; ++j) { fb[j][0] = RDB(1, 2 + j, 0); fb[j][1] = RDB(1, 2 + j, 1); }
    STAGE(0, B1, BT, n0 + 128, t2);
    BAR(); LGKM0();
    __builtin_amdgcn_s_setprio(1);
#pragma unroll
    for (int i = 0; i < 4; ++i)
#pragma unroll
      for (int j = 0; j < 2; ++j) MM(i, 2 + j, i, j);
    __builtin_amdgcn_s_setprio(0);
    BAR();
    // ph7
#pragma unroll
    for (int i = 0; i < 4; ++i) { fa[i][0] = RDA(1, 4 + i, 0); fa[i][1] = RDA(1, 4 + i, 1); }
    BAR(); LGKM0();
    __builtin_amdgcn_s_setprio(1);
#pragma unroll
    for (int i = 0; i < 4; ++i)
#pragma unroll
      for (int j = 0; j < 2; ++j) MM(4 + i, 2 + j, i, j);
    __builtin_amdgcn_s_setprio(0);
    BAR();
    // ph8
#pragma unroll
    for (int j = 0; j < 2; ++j) { fb[j][0] = RDB(1, j, 0); fb[j][1] = RDB(1, j, 1); }
    STAGE(1, A0, A, m0, t3);
    VM2();
    BAR(); LGKM0();
    __builtin_amdgcn_s_setprio(1);
#pragma unroll
    for (int i = 0; i < 4; ++i)
#pragma unroll
      for (int j = 0; j < 2; ++j) MM(4 + i, j, i, j);
    __builtin_amdgcn_s_setprio(0);
    BAR();
  }

#pragma unroll
  for (int mf = 0; mf < 8; ++mf)
#pragma unroll
    for (int nf = 0; nf < 4; ++nf) {
      const int row = m0 + wm * 128 + mf * 16 + lk * 4;
      const int col = n0 + wn * 64 + nf * 16 + lr;
#pragma unroll
      for (int r = 0; r < 4; ++r)
        C[(size_t)(row + r) * ldc + col] = (OUT_T)(acc[mf][nf][r] * scale);
    }
#undef STAGE
#undef RDA
#undef RDB
#undef MM
}

// ================= balanced causal PV: Out = P @ KVT^T =================
// Per batch: M=2048 (64 strips of 32 rows), N=1024, K causal: Kend(strip)=m0+32.
// Block: strip pair {p, 63-p} -> uniform 65*32=2080 K-cols. Tile 32x128, 4 waves.
// XCD remap: blocks sharing (batch, n-slice) contiguous per XCD (KVT L2-resident).
// LDS slot swizzle: 16B-slot ^= (row>>1)&3 on both write (pre-swizzled global
// source) and read -> 2-way banks.
__global__ __launch_bounds__(256) void gemm_pv_bal(const _Float16* __restrict__ P,
                                                   const _Float16* __restrict__ KVT,
                                                   float* __restrict__ Out,
                                                   long sA, long sB, long sC) {
  __shared__ _Float16 As[32 * 32];    // 2 KiB
  __shared__ _Float16 Bs[128 * 32];   // 8 KiB
  // --- bijective XCD-grouped remap ---
  const int total = gridDim.x * gridDim.y * gridDim.z;          // 512 or 1024
  int lin = blockIdx.x + gridDim.x * (blockIdx.y + gridDim.y * blockIdx.z);
  const int xcd = lin & 7, slot = lin >> 3;
  const int G = total >> 8;                                     // grps per XCD
  const int grp = xcd * G + (slot >> 5);                        // (ny, b) group
  const int p = slot & 31;                                      // pair id 0..31
  const int ny = grp & 7, bz = grp >> 3;
  P += (size_t)bz * sA;
  KVT += (size_t)bz * sB;
  Out += (size_t)bz * sC;
  const int n0 = ny * 128;
  const int lane = threadIdx.x & 63, wave = threadIdx.x >> 6;
  const int fr = lane & 15, fc = lane >> 4;
  const int srow = lane >> 2;                                   // staging row 0..15
  const int gslot = ((lane & 3) ^ ((lane >> 3) & 3)) * 8;       // pre-swz src (f16)

#pragma unroll
  for (int half = 0; half < 2; ++half) {
    const int strip = half ? (63 - p) : p;
    const int m0s = strip * 32;
    const int Kend = m0s + 32;
    f32x4 acc[2][2] = {};
    for (int k0 = 0; k0 < Kend; k0 += 32) {
      if (wave < 2)
        glds16(P + (size_t)(m0s + wave * 16 + srow) * 2048 + k0 + gslot, &As[wave * 512]);
      glds16(KVT + (size_t)(n0 + wave * 32 + srow) * 2048 + k0 + gslot, &Bs[wave * 1024]);
      glds16(KVT + (size_t)(n0 + wave * 32 + 16 + srow) * 2048 + k0 + gslot, &Bs[wave * 1024 + 512]);
      __syncthreads();
      f16x8 af[2], bf[2];
#pragma unroll
      for (int m = 0; m < 2; ++m) {
        const int r = m * 16 + fr;
        af[m] = *(const f16x8*)&As[r * 32 + ((fc ^ ((r >> 1) & 3)) << 3)];
      }
#pragma unroll
      for (int n = 0; n < 2; ++n) {
        const int rb = wave * 32 + n * 16 + fr;
        bf[n] = *(const f16x8*)&Bs[rb * 32 + ((fc ^ ((rb >> 1) & 3)) << 3)];
      }
#pragma unroll
      for (int m = 0; m < 2; ++m)
#pragma unroll
        for (int n = 0; n < 2; ++n)
          acc[m][n] = __builtin_amdgcn_mfma_f32_16x16x32_f16(af[m], bf[n], acc[m][n], 0, 0, 0);
      __syncthreads();
    }
#pragma unroll
    for (int m = 0; m < 2; ++m)
#pragma unroll
      for (int n = 0; n < 2; ++n) {
        const int row = m0s + m * 16 + fc * 4;
        const int col = n0 + wave * 32 + n * 16 + fr;
#pragma unroll
        for (int r = 0; r < 4; ++r)
          Out[(size_t)(row + r) * 1024 + col] = acc[m][n][r];
      }
  }
}

// ---------------- softmax over full 2048 row, zero t>s; write only what PV reads
__global__ __launch_bounds__(256) void softmax_mask(_Float16* __restrict__ S) {
  const int row = blockIdx.x;
  const int s = row & 2047;
  _Float16* p = S + (size_t)row * 2048;
  const int tid = threadIdx.x;
  uint4 u = ((const uint4*)p)[tid];
  const _Float16* h = (const _Float16*)&u;
  float v[8];
#pragma unroll
  for (int j = 0; j < 8; ++j) v[j] = (float)h[j];
  float mx = v[0];
#pragma unroll
  for (int j = 1; j < 8; ++j) mx = fmaxf(mx, v[j]);
#pragma unroll
  for (int off = 32; off > 0; off >>= 1) mx = fmaxf(mx, __shfl_xor(mx, off));
  __shared__ float red[8];
  const int wave = tid >> 6, lane = tid & 63;
  if (lane == 0) red[wave] = mx;
  __syncthreads();
  mx = fmaxf(fmaxf(red[0], red[1]), fmaxf(red[2], red[3]));
  float se = 0.f;
#pragma unroll
  for (int j = 0; j < 8; ++j) se += __expf(v[j] - mx);
#pragma unroll
  for (int off = 32; off > 0; off >>= 1) se += __shfl_xor(se, off);
  if (lane == 0) red[4 + wave] = se;
  __syncthreads();
  const float inv = 1.f / (red[4] + red[5] + red[6] + red[7]);
  // PV reads row s only for t < (s & ~31) + 32 (its 32-row strip's Kend).
  const int lim = (s & ~31) + 32;
  if (tid * 8 < lim) {
    _Float16 o[8];
#pragma unroll
    for (int j = 0; j < 8; ++j) {
      int t = tid * 8 + j;
      o[j] = (_Float16)((t <= s) ? __expf(v[j] - mx) * inv : 0.f);
    }
    ((uint4*)p)[tid] = *(const uint4*)o;
  }
}

extern "C" void kernel_launch(void* const* d_in, const int* in_sizes, int n_in,
                              void* d_out, int out_size, void* d_ws, size_t ws_size,
                              hipStream_t stream) {
  const float* x = (const float*)d_in[0];
  const float* wq = (const float*)d_in[1];
  const float* wv = (const float*)d_in[2];
  float* out = (float*)d_out;
  char* ws = (char*)d_ws;

  const size_t MB = 1024 * 1024;
  // bc=4 needs Sc 32MiB + 4x16MiB = 96MiB exactly (proven safe in round 0).
  const int bc = (ws_size >= 96 * MB) ? 4 : 2;
  const size_t scBytes = (size_t)bc * 2048 * 2048 * 2;
  const long PB = 2048 * 1024;
  const long SB = (long)2048 * 2048;

  _Float16* Sc = (_Float16*)ws;
  _Float16* qh = (_Float16*)(ws + scBytes);
  _Float16* kvh = (_Float16*)(ws + scBytes + 16 * MB);
  _Float16* kvvT = (_Float16*)(ws + scBytes + 32 * MB);
  _Float16* kvT = (_Float16*)(ws + scBytes + 48 * MB);
  _Float16* xh = (_Float16*)ws;                 // transient (inside Sc region)
  _Float16* wqh = (_Float16*)(ws + 16 * MB);
  _Float16* wvh = (_Float16*)(ws + 18 * MB);

  // 1) fp32 -> fp16
  cvt_f16<<<8192, 256, 0, stream>>>(x, xh, 2 * 1024 * 1024);
  cvt_f16<<<1024, 256, 0, stream>>>(wq, wqh, 256 * 1024);
  cvt_f16<<<1024, 256, 0, stream>>>(wv, wvh, 256 * 1024);

  // 2) fused qh = xh@wqh^T, kvh = xh@wvh^T
  gemm8p<_Float16><<<dim3(32, 4, 2), 512, 131072, stream>>>(
      xh, wqh, qh, 1024, 1024, 0, (long)(wvh - wqh), (long)(kvh - qh), 1.0f);

  // 3) B^T materialization
  transpose_f16<<<dim3(32, 16, 4), 256, 0, stream>>>(kvh, kvvT, 1024, 2048);
  transpose_f16<<<dim3(16, 32, 4), 256, 0, stream>>>(kvh, kvT, 2048, 1024);

  // 4) per batch-chunk: scores -> softmax+mask -> balanced causal PV
  for (int b0 = 0; b0 < 4; b0 += bc) {
    gemm8p<_Float16><<<dim3(8, 8, bc), 512, 131072, stream>>>(
        qh + (size_t)b0 * PB, kvvT + (size_t)b0 * PB, Sc,
        1024, 2048, PB, PB, SB, 0.03125f);
    softmax_mask<<<bc * 2048, 256, 0, stream>>>(Sc);
    gemm_pv_bal<<<dim3(32, 8, bc), 256, 0, stream>>>(
        Sc, kvT + (size_t)b0 * PB, out + (size_t)b0 * PB, SB, PB, PB);
  }
}

// Round 6
// 146.256 us; speedup vs baseline: 8.4549x; 1.0889x over previous
//
#include <hip/hip_runtime.h>

// B=4, S=2048, D=1024, fp32 in/out.
// q = x@wq^T; kv = x@wv^T; Sc = q @ reshape(kv,[D,S]) / 32 (raw reshape!);
// P = softmax(Sc, full row); P = tril(P) (post-softmax, no renorm); out = P@kv.
//
// Engines:
//  - gemm8p: 256x256, BK=64, 8 waves, 8-phase counted-vmcnt, XOR-swizzled LDS.
//  - gemm_pv_bal: balanced causal PV, 64x128 tile, BK=64, double-buffered LDS
//    (stage-ahead + single barrier/step), strip pairs (p,31-p) -> uniform 33
//    K-steps; XCD-grouped remap; gemm8p-style row&7 XOR swizzle both sides.
// ws (96 MiB): Sc[bc*8MiB] | qh 16 | kvh 16 | kvvT 16 | kvT 16.

typedef __attribute__((ext_vector_type(8))) _Float16 f16x8;
typedef __attribute__((ext_vector_type(4))) _Float16 f16x4;
typedef __attribute__((ext_vector_type(4))) float f32x4;

__device__ __forceinline__ void glds16(const void* g, void* l) {
  __builtin_amdgcn_global_load_lds((const __attribute__((address_space(1))) void*)g,
                                   (__attribute__((address_space(3))) void*)l, 16, 0, 0);
}
#define BAR() __builtin_amdgcn_s_barrier()
#define LGKM0() do { asm volatile("s_waitcnt lgkmcnt(0)" ::: "memory"); \
                     __builtin_amdgcn_sched_barrier(0); } while (0)
#define VM2() asm volatile("s_waitcnt vmcnt(2)" ::: "memory")
#define VM0() asm volatile("s_waitcnt vmcnt(0)" ::: "memory")

// ---------------- fp32 -> fp16 convert
__global__ __launch_bounds__(256) void cvt_f16(const float* __restrict__ in,
                                               _Float16* __restrict__ out, int n4) {
  int i = blockIdx.x * 256 + threadIdx.x;
  if (i < n4) {
    float4 v = ((const float4*)in)[i];
    f16x4 o = {(_Float16)v.x, (_Float16)v.y, (_Float16)v.z, (_Float16)v.w};
    ((f16x4*)out)[i] = o;
  }
}

// ---------------- tiled fp16 transpose: out[c][r] = in[r][c], per blockIdx.z slab
__global__ __launch_bounds__(256) void transpose_f16(const _Float16* __restrict__ in,
                                                     _Float16* __restrict__ out,
                                                     int R, int C) {
  __shared__ _Float16 T[64][65];
  const size_t off = (size_t)blockIdx.z * R * C;
  const _Float16* I = in + off;
  _Float16* O = out + off;
  const int c0 = blockIdx.x * 64, r0 = blockIdx.y * 64;
  const int t = threadIdx.x;
#pragma unroll
  for (int i = 0; i < 2; ++i) {
    int lin = (t + i * 256) * 8;
    int r = lin >> 6, c = lin & 63;
    uint4 v = *(const uint4*)(I + (size_t)(r0 + r) * C + c0 + c);
    const _Float16* h = (const _Float16*)&v;
#pragma unroll
    for (int j = 0; j < 8; ++j) T[r][c + j] = h[j];
  }
  __syncthreads();
#pragma unroll
  for (int i = 0; i < 2; ++i) {
    int lin = (t + i * 256) * 8;
    int cc = lin >> 6, rr = lin & 63;
    _Float16 o[8];
#pragma unroll
    for (int j = 0; j < 8; ++j) o[j] = T[rr + j][cc];
    *(uint4*)(O + (size_t)(c0 + cc) * R + r0 + rr) = *(const uint4*)o;
  }
}

// ================= 8-phase 256^2 MFMA GEMM: C = scale * (A @ BT^T) =================
template <typename OUT_T>
__global__ __launch_bounds__(512, 2) void gemm8p(const _Float16* __restrict__ A,
                                                 const _Float16* __restrict__ BT,
                                                 OUT_T* __restrict__ C,
                                                 int K, int ldc,
                                                 long sA, long sB, long sC, float scale) {
  extern __shared__ char smem[];
  _Float16* lds = (_Float16*)smem;
  A += (size_t)blockIdx.z * sA;
  BT += (size_t)blockIdx.z * sB;
  C += (size_t)blockIdx.z * sC;
  const int m0 = blockIdx.x << 8, n0 = blockIdx.y << 8;
  const int tid = threadIdx.x, lane = tid & 63, wave = tid >> 6;
  const int wm = wave >> 2, wn = wave & 3;
  const int lr = lane & 15, lk = lane >> 4, xr = lane & 7;
  const int nkt = K >> 6;
  const int A0 = 0, A1 = 8192, B0 = 16384, B1 = 24576, BUF = 32768;
  const int baseA = wm ? A1 : A0;
  const int baseB = B0 + ((wn >> 1) << 13);
  const int bRow = (wn & 1) << 6;
  const int srow = lane >> 3;
  const int scolB = ((lane & 7) << 4) ^ (srow << 4);

  f32x4 acc[8][4] = {};
  f16x8 fa[4][2], fb[2][2];

#define STAGE(bufsel, halfsel, G, hrow0, kt) do {                                   \
    const _Float16* _g = (G) + (size_t)((hrow0) + wave * 16 + srow) * K + ((kt) << 6); \
    glds16((const char*)_g + scolB, (char*)&lds[(bufsel) * BUF + (halfsel) + wave * 1024]);        \
    glds16((const char*)(_g + (size_t)8 * K) + scolB,                                \
           (char*)&lds[(bufsel) * BUF + (halfsel) + wave * 1024 + 512]);             \
  } while (0)
#define RDA(buf, mf, ks) (*(const f16x8*)&lds[(buf) * BUF + baseA + ((mf) * 16 + lr) * 64 + \
                                              ((((ks) * 4 + lk) ^ xr) << 3)])
#define RDB(buf, nf, ks) (*(const f16x8*)&lds[(buf) * BUF + baseB + (bRow + (nf) * 16 + lr) * 64 + \
                                              ((((ks) * 4 + lk) ^ xr) << 3)])
#define MM(i, j, ks0, ks1) do {                                                      \
    acc[i][j] = __builtin_amdgcn_mfma_f32_16x16x32_f16(fa[ks0][0], fb[ks1][0], acc[i][j], 0, 0, 0); \
    acc[i][j] = __builtin_amdgcn_mfma_f32_16x16x32_f16(fa[ks0][1], fb[ks1][1], acc[i][j], 0, 0, 0); \
  } while (0)

  STAGE(0, A0, A, m0, 0);
  STAGE(0, A1, A, m0 + 128, 0);
  STAGE(0, B0, BT, n0, 0);
  STAGE(0, B1, BT, n0 + 128, 0);
  STAGE(1, A0, A, m0, 1);
  VM2();
  BAR();

  for (int it = 0; it < (nkt >> 1); ++it) {
    const int t = it << 1;
    const int t2 = (t + 2 < nkt) ? t + 2 : 0;
    const int t3 = (t + 3 < nkt) ? t + 3 : 0;
    // ph1
#pragma unroll
    for (int i = 0; i < 4; ++i) { fa[i][0] = RDA(0, i, 0); fa[i][1] = RDA(0, i, 1); }
#pragma unroll
    for (int j = 0; j < 2; ++j) { fb[j][0] = RDB(0, j, 0); fb[j][1] = RDB(0, j, 1); }
    STAGE(1, A1, A, m0 + 128, t + 1);
    STAGE(1, B0, BT, n0, t + 1);
    BAR(); LGKM0();
    __builtin_amdgcn_s_setprio(1);
#pragma unroll
    for (int i = 0; i < 4; ++i)
#pragma unroll
      for (int j = 0; j < 2; ++j) MM(i, j, i, j);
    __builtin_amdgcn_s_setprio(0);
    BAR();
    // ph2
#pragma unroll
    for (int j = 0; j < 2; ++j) { fb[j][0] = RDB(0, 2 + j, 0); fb[j][1] = RDB(0, 2 + j, 1); }
    STAGE(1, B1, BT, n0 + 128, t + 1);
    BAR(); LGKM0();
    __builtin_amdgcn_s_setprio(1);
#pragma unroll
    for (int i = 0; i < 4; ++i)
#pragma unroll
      for (int j = 0; j < 2; ++j) MM(i, 2 + j, i, j);
    __builtin_amdgcn_s_setprio(0);
    BAR();
    // ph3
#pragma unroll
    for (int i = 0; i < 4; ++i) { fa[i][0] = RDA(0, 4 + i, 0); fa[i][1] = RDA(0, 4 + i, 1); }
    BAR(); LGKM0();
    __builtin_amdgcn_s_setprio(1);
#pragma unroll
    for (int i = 0; i < 4; ++i)
#pragma unroll
      for (int j = 0; j < 2; ++j) MM(4 + i, 2 + j, i, j);
    __builtin_amdgcn_s_setprio(0);
    BAR();
    // ph4
#pragma unroll
    for (int j = 0; j < 2; ++j) { fb[j][0] = RDB(0, j, 0); fb[j][1] = RDB(0, j, 1); }
    STAGE(0, A0, A, m0, t2);
    VM2();
    BAR(); LGKM0();
    __builtin_amdgcn_s_setprio(1);
#pragma unroll
    for (int i = 0; i < 4; ++i)
#pragma unroll
      for (int j = 0; j < 2; ++j) MM(4 + i, j, i, j);
    __builtin_amdgcn_s_setprio(0);
    BAR();
    // ph5
#pragma unroll
    for (int i = 0; i < 4; ++i) { fa[i][0] = RDA(1, i, 0); fa[i][1] = RDA(1, i, 1); }
#pragma unroll
    for (int j = 0; j < 2; ++j) { fb[j][0] = RDB(1, j, 0); fb[j][1] = RDB(1, j, 1); }
    STAGE(0, A1, A, m0 + 128, t2);
    STAGE(0, B0, BT, n0, t2);
    BAR(); LGKM0();
    __builtin_amdgcn_s_setprio(1);
#pragma unroll
    for (int i = 0; i < 4; ++i)
#pragma unroll
      for (int j = 0; j < 2; ++j) MM(i, j, i, j);
    __builtin_amdgcn_s_setprio(0);
    BAR();
    // ph6
#pragma unroll
    for (int j = 0; j < 2; ++j) { fb[j][0] = RDB(1, 2 + j, 0); fb[j][1] = RDB(1, 2 + j, 1); }
    STAGE(0, B1, BT, n0 + 128, t2);
    BAR(); LGKM0();
    __builtin_amdgcn_s_setprio(1);
#pragma unroll
    for (int i = 0; i < 4; ++i)
#pragma unroll
      for (int j = 0; j < 2; ++j) MM(i, 2 + j, i, j);
    __builtin_amdgcn_s_setprio(0);
    BAR();
    // ph7
#pragma unroll
    for (int i = 0; i < 4; ++i) { fa[i][0] = RDA(1, 4 + i, 0); fa[i][1] = RDA(1, 4 + i, 1); }
    BAR(); LGKM0();
    __builtin_amdgcn_s_setprio(1);
#pragma unroll
    for (int i = 0; i < 4; ++i)
#pragma unroll
      for (int j = 0; j < 2; ++j) MM(4 + i, 2 + j, i, j);
    __builtin_amdgcn_s_setprio(0);
    BAR();
    // ph8
#pragma unroll
    for (int j = 0; j < 2; ++j) { fb[j][0] = RDB(1, j, 0); fb[j][1] = RDB(1, j, 1); }
    STAGE(1, A0, A, m0, t3);
    VM2();
    BAR(); LGKM0();
    __builtin_amdgcn_s_setprio(1);
#pragma unroll
    for (int i = 0; i < 4; ++i)
#pragma unroll
      for (int j = 0; j < 2; ++j) MM(4 + i, j, i, j);
    __builtin_amdgcn_s_setprio(0);
    BAR();
  }

#pragma unroll
  for (int mf = 0; mf < 8; ++mf)
#pragma unroll
    for (int nf = 0; nf < 4; ++nf) {
      const int row = m0 + wm * 128 + mf * 16 + lk * 4;
      const int col = n0 + wn * 64 + nf * 16 + lr;
#pragma unroll
      for (int r = 0; r < 4; ++r)
        C[(size_t)(row + r) * ldc + col] = (OUT_T)(acc[mf][nf][r] * scale);
    }
#undef STAGE
#undef RDA
#undef RDB
#undef MM
}

// ================= balanced causal PV: Out = P @ KVT^T (double-buffered) =========
// Per batch: M=2048 (32 strips of 64 rows), N=1024, Kend(strip)=64*(strip+1).
// Block handles pair {p, 31-p}: uniform 33 K-steps of 64. Tile 64x128, 4 waves.
// LDS: A[2][64*64] 16KB + B[2][128*64] 32KB = 48KB -> 3 blocks/CU.
// Swizzle: 16B slot ^= (row&7), pre-swizzled global source (both-sides XOR).
// XCD remap: 16 pair-blocks sharing (ny,b) KVT slice grouped per XCD.
__global__ __launch_bounds__(256) void gemm_pv_bal(const _Float16* __restrict__ P,
                                                   const _Float16* __restrict__ KVT,
                                                   float* __restrict__ Out,
                                                   long sA, long sB, long sC) {
  __shared__ _Float16 As[2][64 * 64];
  __shared__ _Float16 Bs[2][128 * 64];
  // --- bijective XCD-grouped remap: lin -> (xcd, slot); 16 pairs per group ---
  const int total = gridDim.x * gridDim.y * gridDim.z;          // 128*bc
  int lin = blockIdx.x + gridDim.x * (blockIdx.y + gridDim.y * blockIdx.z);
  const int xcd = lin & 7, slot = lin >> 3;
  const int perx = total >> 7;                                  // groups per XCD
  const int grp = xcd * perx + (slot >> 4);
  const int p = slot & 15;
  const int ny = grp & 7, bz = grp >> 3;
  P += (size_t)bz * sA;
  KVT += (size_t)bz * sB;
  Out += (size_t)bz * sC;
  const int n0 = ny * 128;
  const int lane = threadIdx.x & 63, wave = threadIdx.x >> 6;
  const int fr = lane & 15, lk = lane >> 4;
  const int srow = lane >> 3;                                   // row in 8-row chunk
  const int scol = (((lane & 7) ^ srow) << 4);                  // pre-swz src byte

  // stage one K-step (64 cols) of A (8 chunks) + B (16 chunks); 6 glds/wave
#define PSTAGE(buf, m0s, t) do {                                                     \
    const int _k0 = (t) << 6;                                                        \
    _Pragma("unroll")                                                                \
    for (int c = 0; c < 2; ++c) {                                                    \
      const int ch = wave * 2 + c;                                                   \
      glds16((const char*)(P + (size_t)((m0s) + ch * 8 + srow) * 2048 + _k0) + scol, \
             &As[buf][ch * 512]);                                                    \
    }                                                                                \
    _Pragma("unroll")                                                                \
    for (int c = 0; c < 4; ++c) {                                                    \
      const int ch = wave * 4 + c;                                                   \
      glds16((const char*)(KVT + (size_t)(n0 + ch * 8 + srow) * 2048 + _k0) + scol,  \
             &Bs[buf][ch * 512]);                                                    \
    }                                                                                \
  } while (0)

#pragma unroll
  for (int half = 0; half < 2; ++half) {
    const int strip = half ? (31 - p) : p;
    const int m0s = strip * 64;
    const int nt = strip + 1;                 // K-steps of 64
    f32x4 acc[4][2] = {};
    PSTAGE(0, m0s, 0);
    VM0();
    BAR();
    for (int t = 0; t < nt; ++t) {
      const int cur = t & 1;
      if (t + 1 < nt) PSTAGE(cur ^ 1, m0s, t + 1);
      f16x8 af[4][2], bf[2][2];
#pragma unroll
      for (int m = 0; m < 4; ++m) {
        const int r = m * 16 + fr;
#pragma unroll
        for (int ks = 0; ks < 2; ++ks)
          af[m][ks] = *(const f16x8*)&As[cur][r * 64 + (((ks * 4 + lk) ^ (r & 7)) << 3)];
      }
#pragma unroll
      for (int n = 0; n < 2; ++n) {
        const int rb = wave * 32 + n * 16 + fr;
#pragma unroll
        for (int ks = 0; ks < 2; ++ks)
          bf[n][ks] = *(const f16x8*)&Bs[cur][rb * 64 + (((ks * 4 + lk) ^ (rb & 7)) << 3)];
      }
      LGKM0();
      __builtin_amdgcn_s_setprio(1);
#pragma unroll
      for (int ks = 0; ks < 2; ++ks)
#pragma unroll
        for (int m = 0; m < 4; ++m)
#pragma unroll
          for (int n = 0; n < 2; ++n)
            acc[m][n] = __builtin_amdgcn_mfma_f32_16x16x32_f16(af[m][ks], bf[n][ks],
                                                               acc[m][n], 0, 0, 0);
      __builtin_amdgcn_s_setprio(0);
      VM0();                                  // next-step stage landed
      BAR();                                  // all waves done with As/Bs[cur]
    }
#pragma unroll
    for (int m = 0; m < 4; ++m)
#pragma unroll
      for (int n = 0; n < 2; ++n) {
        const int row = m0s + m * 16 + lk * 4;
        const int col = n0 + wave * 32 + n * 16 + fr;
#pragma unroll
        for (int r = 0; r < 4; ++r)
          Out[(size_t)(row + r) * 1024 + col] = acc[m][n][r];
      }
  }
#undef PSTAGE
}

// ---------------- softmax over full 2048 row, zero t>s; write only what PV reads
__global__ __launch_bounds__(256) void softmax_mask(_Float16* __restrict__ S) {
  const int row = blockIdx.x;
  const int s = row & 2047;
  _Float16* p = S + (size_t)row * 2048;
  const int tid = threadIdx.x;
  uint4 u = ((const uint4*)p)[tid];
  const _Float16* h = (const _Float16*)&u;
  float v[8];
#pragma unroll
  for (int j = 0; j < 8; ++j) v[j] = (float)h[j];
  float mx = v[0];
#pragma unroll
  for (int j = 1; j < 8; ++j) mx = fmaxf(mx, v[j]);
#pragma unroll
  for (int off = 32; off > 0; off >>= 1) mx = fmaxf(mx, __shfl_xor(mx, off));
  __shared__ float red[8];
  const int wave = tid >> 6, lane = tid & 63;
  if (lane == 0) red[wave] = mx;
  __syncthreads();
  mx = fmaxf(fmaxf(red[0], red[1]), fmaxf(red[2], red[3]));
  float se = 0.f;
#pragma unroll
  for (int j = 0; j < 8; ++j) se += __expf(v[j] - mx);
#pragma unroll
  for (int off = 32; off > 0; off >>= 1) se += __shfl_xor(se, off);
  if (lane == 0) red[4 + wave] = se;
  __syncthreads();
  const float inv = 1.f / (red[4] + red[5] + red[6] + red[7]);
  // PV reads row s only for t < (s & ~63) + 64 (its 64-row strip's Kend).
  const int lim = (s & ~63) + 64;
  if (tid * 8 < lim) {
    _Float16 o[8];
#pragma unroll
    for (int j = 0; j < 8; ++j) {
      int t = tid * 8 + j;
      o[j] = (_Float16)((t <= s) ? __expf(v[j] - mx) * inv : 0.f);
    }
    ((uint4*)p)[tid] = *(const uint4*)o;
  }
}

extern "C" void kernel_launch(void* const* d_in, const int* in_sizes, int n_in,
                              void* d_out, int out_size, void* d_ws, size_t ws_size,
                              hipStream_t stream) {
  const float* x = (const float*)d_in[0];
  const float* wq = (const float*)d_in[1];
  const float* wv = (const float*)d_in[2];
  float* out = (float*)d_out;
  char* ws = (char*)d_ws;

  const size_t MB = 1024 * 1024;
  const int bc = (ws_size >= 96 * MB) ? 4 : 2;
  const size_t scBytes = (size_t)bc * 2048 * 2048 * 2;
  const long PB = 2048 * 1024;
  const long SB = (long)2048 * 2048;

  _Float16* Sc = (_Float16*)ws;
  _Float16* qh = (_Float16*)(ws + scBytes);
  _Float16* kvh = (_Float16*)(ws + scBytes + 16 * MB);
  _Float16* kvvT = (_Float16*)(ws + scBytes + 32 * MB);
  _Float16* kvT = (_Float16*)(ws + scBytes + 48 * MB);
  _Float16* xh = (_Float16*)ws;                 // transient (inside Sc region)
  _Float16* wqh = (_Float16*)(ws + 16 * MB);
  _Float16* wvh = (_Float16*)(ws + 18 * MB);

  // 1) fp32 -> fp16
  cvt_f16<<<8192, 256, 0, stream>>>(x, xh, 2 * 1024 * 1024);
  cvt_f16<<<1024, 256, 0, stream>>>(wq, wqh, 256 * 1024);
  cvt_f16<<<1024, 256, 0, stream>>>(wv, wvh, 256 * 1024);

  // 2) fused qh = xh@wqh^T, kvh = xh@wvh^T
  gemm8p<_Float16><<<dim3(32, 4, 2), 512, 131072, stream>>>(
      xh, wqh, qh, 1024, 1024, 0, (long)(wvh - wqh), (long)(kvh - qh), 1.0f);

  // 3) B^T materialization
  transpose_f16<<<dim3(32, 16, 4), 256, 0, stream>>>(kvh, kvvT, 1024, 2048);
  transpose_f16<<<dim3(16, 32, 4), 256, 0, stream>>>(kvh, kvT, 2048, 1024);

  // 4) per batch-chunk: scores -> softmax+mask -> balanced causal PV
  for (int b0 = 0; b0 < 4; b0 += bc) {
    gemm8p<_Float16><<<dim3(8, 8, bc), 512, 131072, stream>>>(
        qh + (size_t)b0 * PB, kvvT + (size_t)b0 * PB, Sc,
        1024, 2048, PB, PB, SB, 0.03125f);
    softmax_mask<<<bc * 2048, 256, 0, stream>>>(Sc);
    gemm_pv_bal<<<dim3(16, 8, bc), 256, 0, stream>>>(
        Sc, kvT + (size_t)b0 * PB, out + (size_t)b0 * PB, SB, PB, PB);
  }
}

// Round 7
// 144.419 us; speedup vs baseline: 8.5624x; 1.0127x over previous
//
#include <hip/hip_runtime.h>

// B=4, S=2048, D=1024, fp32 in/out.
// q = x@wq^T; kv = x@wv^T; Sc = q @ reshape(kv,[D,S]) / 32 (raw reshape!);
// P = softmax(Sc, full row); P = tril(P) (post-softmax, no renorm); out = P@kv.
//
// Engines:
//  - gemm8p: 256x256, BK=64, 8 waves, 8-phase counted-vmcnt, XOR-swizzled LDS.
//    R7: B-fragments held in regs (read once/K-tile, -25% LDS traffic) +
//    bijective XCD-grouped remap (B-panel L2 residency).
//  - gemm_pv_bal: balanced causal PV, 64x128, BK=64, double-buffered.
// ws (96 MiB): Sc[bc*8MiB] | qh 16 | kvh 16 | kvvT 16 | kvT 16.

typedef __attribute__((ext_vector_type(8))) _Float16 f16x8;
typedef __attribute__((ext_vector_type(4))) _Float16 f16x4;
typedef __attribute__((ext_vector_type(4))) float f32x4;

__device__ __forceinline__ void glds16(const void* g, void* l) {
  __builtin_amdgcn_global_load_lds((const __attribute__((address_space(1))) void*)g,
                                   (__attribute__((address_space(3))) void*)l, 16, 0, 0);
}
#define BAR() __builtin_amdgcn_s_barrier()
#define LGKM0() do { asm volatile("s_waitcnt lgkmcnt(0)" ::: "memory"); \
                     __builtin_amdgcn_sched_barrier(0); } while (0)
#define VM2() asm volatile("s_waitcnt vmcnt(2)" ::: "memory")
#define VM0() asm volatile("s_waitcnt vmcnt(0)" ::: "memory")
#define PR1() __builtin_amdgcn_s_setprio(1)
#define PR0() __builtin_amdgcn_s_setprio(0)

// ---------------- fp32 -> fp16 convert (x, wq, wv fused; float4 granules)
__global__ __launch_bounds__(256) void cvt3(const float* __restrict__ x,
                                            const float* __restrict__ wq,
                                            const float* __restrict__ wv,
                                            _Float16* __restrict__ xh,
                                            _Float16* __restrict__ wqh,
                                            _Float16* __restrict__ wvh) {
  int i = blockIdx.x * 256 + threadIdx.x;
  const float* src;
  _Float16* dst;
  int off;
  if (i < 2097152) { src = x; dst = xh; off = i; }
  else if (i < 2359296) { src = wq; dst = wqh; off = i - 2097152; }
  else { src = wv; dst = wvh; off = i - 2359296; }
  float4 v = ((const float4*)src)[off];
  f16x4 o = {(_Float16)v.x, (_Float16)v.y, (_Float16)v.z, (_Float16)v.w};
  ((f16x4*)dst)[off] = o;
}

// ---------------- tiled fp16 transpose: out[c][r] = in[r][c], per blockIdx.z slab
__global__ __launch_bounds__(256) void transpose_f16(const _Float16* __restrict__ in,
                                                     _Float16* __restrict__ out,
                                                     int R, int C) {
  __shared__ _Float16 T[64][65];
  const size_t off = (size_t)blockIdx.z * R * C;
  const _Float16* I = in + off;
  _Float16* O = out + off;
  const int c0 = blockIdx.x * 64, r0 = blockIdx.y * 64;
  const int t = threadIdx.x;
#pragma unroll
  for (int i = 0; i < 2; ++i) {
    int lin = (t + i * 256) * 8;
    int r = lin >> 6, c = lin & 63;
    uint4 v = *(const uint4*)(I + (size_t)(r0 + r) * C + c0 + c);
    const _Float16* h = (const _Float16*)&v;
#pragma unroll
    for (int j = 0; j < 8; ++j) T[r][c + j] = h[j];
  }
  __syncthreads();
#pragma unroll
  for (int i = 0; i < 2; ++i) {
    int lin = (t + i * 256) * 8;
    int cc = lin >> 6, rr = lin & 63;
    _Float16 o[8];
#pragma unroll
    for (int j = 0; j < 8; ++j) o[j] = T[rr + j][cc];
    *(uint4*)(O + (size_t)(c0 + cc) * R + r0 + rr) = *(const uint4*)o;
  }
}

// ================= 8-phase 256^2 MFMA GEMM: C = scale * (A @ BT^T) =================
// XCD remap: lin -> xcd = lin&7, slot s = lin>>3; mx = s & (2^lgx - 1);
// panel pid = xcd*G + (s>>lgx), G = NY*NZ/8; ny = pid & (NY-1); bz = pid >> lgy.
// Blocks sharing a B-panel (ny,bz) land on one XCD.
template <typename OUT_T>
__global__ __launch_bounds__(512, 2) void gemm8p(const _Float16* __restrict__ A,
                                                 const _Float16* __restrict__ BT,
                                                 OUT_T* __restrict__ C,
                                                 int K, int ldc,
                                                 long sA, long sB, long sC, float scale,
                                                 int lgx, int lgy) {
  extern __shared__ char smem[];
  _Float16* lds = (_Float16*)smem;
  {
    int lin = blockIdx.x + gridDim.x * (blockIdx.y + gridDim.y * blockIdx.z);
    const int xcd = lin & 7, s = lin >> 3;
    const int G = (gridDim.y * gridDim.z) >> 3;
    const int mx = s & ((1 << lgx) - 1);
    const int pid = xcd * G + (s >> lgx);
    const int ny = pid & (gridDim.y - 1);
    const int bz = pid >> lgy;
    A += (size_t)bz * sA;
    BT += (size_t)bz * sB;
    C += (size_t)bz * sC;
    // store tile origins via lane-uniform regs
    lin = 0;
    A += (size_t)0;
    // m0/n0 set below
    __builtin_amdgcn_sched_barrier(0);
    // fallthrough with mx, ny captured:
    // (kept in scope via variables declared next)
    static_assert(true, "");
    // declare outside block instead
    // -- handled below --
    // NOTE: we re-derive m0/n0 here:
    // (block scope trick: assign to outer variables)
    // see m0/n0 decl
    goto after_remap;
  after_remap:;
    // m0, n0 assigned after block via captured values:
    // (we simply shadow: declare real m0/n0 now)
    // -- actual declarations:
    const int m0_ = mx << 8, n0_ = ny << 8;
    // continue kernel with m0_, n0_
    const int tid = threadIdx.x, lane = tid & 63, wave = tid >> 6;
    const int wm = wave >> 2, wn = wave & 3;
    const int lr = lane & 15, lk = lane >> 4, xr = lane & 7;
    const int nkt = K >> 6;
    const int A0 = 0, A1 = 8192, B0 = 16384, B1 = 24576, BUF = 32768;
    const int baseA = wm ? A1 : A0;
    const int baseB = B0 + ((wn >> 1) << 13);
    const int bRow = (wn & 1) << 6;
    const int srow = lane >> 3;
    const int scolB = ((lane & 7) << 4) ^ (srow << 4);
    const int m0 = m0_, n0 = n0_;

    f32x4 acc[8][4] = {};
    f16x8 fa[4][2], fb[4][2];

#define STAGE(bufsel, halfsel, G_, hrow0, kt) do {                                   \
    const _Float16* _g = (G_) + (size_t)((hrow0) + wave * 16 + srow) * K + ((kt) << 6); \
    glds16((const char*)_g + scolB, (char*)&lds[(bufsel) * BUF + (halfsel) + wave * 1024]); \
    glds16((const char*)(_g + (size_t)8 * K) + scolB,                                \
           (char*)&lds[(bufsel) * BUF + (halfsel) + wave * 1024 + 512]);             \
  } while (0)
#define RDA(buf, mf, ks) (*(const f16x8*)&lds[(buf) * BUF + baseA + ((mf) * 16 + lr) * 64 + \
                                              ((((ks) * 4 + lk) ^ xr) << 3)])
#define RDB(buf, nf, ks) (*(const f16x8*)&lds[(buf) * BUF + baseB + (bRow + (nf) * 16 + lr) * 64 + \
                                              ((((ks) * 4 + lk) ^ xr) << 3)])
#define RDFA4(b, mbase) do { _Pragma("unroll")                                        \
    for (int i = 0; i < 4; ++i) { fa[i][0] = RDA(b, (mbase) + i, 0);                  \
                                  fa[i][1] = RDA(b, (mbase) + i, 1); } } while (0)
#define RDFB2(b, jbase) do { _Pragma("unroll")                                        \
    for (int j = 0; j < 2; ++j) { fb[(jbase) + j][0] = RDB(b, (jbase) + j, 0);        \
                                  fb[(jbase) + j][1] = RDB(b, (jbase) + j, 1); } } while (0)
#define MMQ(ib, jb) do { _Pragma("unroll")                                            \
    for (int i = 0; i < 4; ++i) { _Pragma("unroll")                                   \
      for (int j = 0; j < 2; ++j) {                                                   \
        acc[(ib) + i][(jb) + j] = __builtin_amdgcn_mfma_f32_16x16x32_f16(             \
            fa[i][0], fb[(jb) + j][0], acc[(ib) + i][(jb) + j], 0, 0, 0);             \
        acc[(ib) + i][(jb) + j] = __builtin_amdgcn_mfma_f32_16x16x32_f16(             \
            fa[i][1], fb[(jb) + j][1], acc[(ib) + i][(jb) + j], 0, 0, 0);             \
      } } } while (0)

    // prologue: tile0 -> buf0 (4 halves), tile1.A0 -> buf1; wait tile0 landed.
    STAGE(0, A0, A, m0, 0);
    STAGE(0, A1, A, m0 + 128, 0);
    STAGE(0, B0, BT, n0, 0);
    STAGE(0, B1, BT, n0 + 128, 0);
    STAGE(1, A0, A, m0, 1);
    VM2();
    BAR();

    for (int it = 0; it < (nkt >> 1); ++it) {
      const int t = it << 1;
      const int t2 = (t + 2 < nkt) ? t + 2 : 0;
      const int t3 = (t + 3 < nkt) ? t + 3 : 0;
      // ---- K-tile t (buf0) ----
      RDFA4(0, 0); RDFB2(0, 0);
      STAGE(1, A1, A, m0 + 128, t + 1);
      STAGE(1, B0, BT, n0, t + 1);
      BAR(); LGKM0(); PR1(); MMQ(0, 0); PR0(); BAR();
      RDFB2(0, 2);
      STAGE(1, B1, BT, n0 + 128, t + 1);
      BAR(); LGKM0(); PR1(); MMQ(0, 2); PR0(); BAR();
      RDFA4(0, 4);
      BAR(); LGKM0(); PR1(); MMQ(4, 2); PR0(); BAR();
      STAGE(0, A0, A, m0, t2);
      VM2();
      BAR(); PR1(); MMQ(4, 0); PR0(); BAR();
      // ---- K-tile t+1 (buf1) ----
      RDFA4(1, 0); RDFB2(1, 0);
      STAGE(0, A1, A, m0 + 128, t2);
      STAGE(0, B0, BT, n0, t2);
      BAR(); LGKM0(); PR1(); MMQ(0, 0); PR0(); BAR();
      RDFB2(1, 2);
      STAGE(0, B1, BT, n0 + 128, t2);
      BAR(); LGKM0(); PR1(); MMQ(0, 2); PR0(); BAR();
      RDFA4(1, 4);
      BAR(); LGKM0(); PR1(); MMQ(4, 2); PR0(); BAR();
      STAGE(1, A0, A, m0, t3);
      VM2();
      BAR(); PR1(); MMQ(4, 0); PR0(); BAR();
    }

    // epilogue
#pragma unroll
    for (int mf = 0; mf < 8; ++mf)
#pragma unroll
      for (int nf = 0; nf < 4; ++nf) {
        const int row = m0 + wm * 128 + mf * 16 + lk * 4;
        const int col = n0 + wn * 64 + nf * 16 + lr;
#pragma unroll
        for (int r = 0; r < 4; ++r)
          C[(size_t)(row + r) * ldc + col] = (OUT_T)(acc[mf][nf][r] * scale);
      }
#undef STAGE
#undef RDA
#undef RDB
#undef RDFA4
#undef RDFB2
#undef MMQ
  }
}

// ================= balanced causal PV: Out = P @ KVT^T (double-buffered) =========
__global__ __launch_bounds__(256) void gemm_pv_bal(const _Float16* __restrict__ P,
                                                   const _Float16* __restrict__ KVT,
                                                   float* __restrict__ Out,
                                                   long sA, long sB, long sC) {
  __shared__ _Float16 As[2][64 * 64];
  __shared__ _Float16 Bs[2][128 * 64];
  const int total = gridDim.x * gridDim.y * gridDim.z;
  int lin = blockIdx.x + gridDim.x * (blockIdx.y + gridDim.y * blockIdx.z);
  const int xcd = lin & 7, slot = lin >> 3;
  const int perx = total >> 7;
  const int grp = xcd * perx + (slot >> 4);
  const int p = slot & 15;
  const int ny = grp & 7, bz = grp >> 3;
  P += (size_t)bz * sA;
  KVT += (size_t)bz * sB;
  Out += (size_t)bz * sC;
  const int n0 = ny * 128;
  const int lane = threadIdx.x & 63, wave = threadIdx.x >> 6;
  const int fr = lane & 15, lk = lane >> 4;
  const int srow = lane >> 3;
  const int scol = (((lane & 7) ^ srow) << 4);

#define PSTAGE(buf, m0s, t) do {                                                     \
    const int _k0 = (t) << 6;                                                        \
    _Pragma("unroll")                                                                \
    for (int c = 0; c < 2; ++c) {                                                    \
      const int ch = wave * 2 + c;                                                   \
      glds16((const char*)(P + (size_t)((m0s) + ch * 8 + srow) * 2048 + _k0) + scol, \
             &As[buf][ch * 512]);                                                    \
    }                                                                                \
    _Pragma("unroll")                                                                \
    for (int c = 0; c < 4; ++c) {                                                    \
      const int ch = wave * 4 + c;                                                   \
      glds16((const char*)(KVT + (size_t)(n0 + ch * 8 + srow) * 2048 + _k0) + scol,  \
             &Bs[buf][ch * 512]);                                                    \
    }                                                                                \
  } while (0)

#pragma unroll
  for (int half = 0; half < 2; ++half) {
    const int strip = half ? (31 - p) : p;
    const int m0s = strip * 64;
    const int nt = strip + 1;
    f32x4 acc[4][2] = {};
    PSTAGE(0, m0s, 0);
    VM0();
    BAR();
    for (int t = 0; t < nt; ++t) {
      const int cur = t & 1;
      if (t + 1 < nt) PSTAGE(cur ^ 1, m0s, t + 1);
      f16x8 af[4][2], bf[2][2];
#pragma unroll
      for (int m = 0; m < 4; ++m) {
        const int r = m * 16 + fr;
#pragma unroll
        for (int ks = 0; ks < 2; ++ks)
          af[m][ks] = *(const f16x8*)&As[cur][r * 64 + (((ks * 4 + lk) ^ (r & 7)) << 3)];
      }
#pragma unroll
      for (int n = 0; n < 2; ++n) {
        const int rb = wave * 32 + n * 16 + fr;
#pragma unroll
        for (int ks = 0; ks < 2; ++ks)
          bf[n][ks] = *(const f16x8*)&Bs[cur][rb * 64 + (((ks * 4 + lk) ^ (rb & 7)) << 3)];
      }
      LGKM0();
      PR1();
#pragma unroll
      for (int ks = 0; ks < 2; ++ks)
#pragma unroll
        for (int m = 0; m < 4; ++m)
#pragma unroll
          for (int n = 0; n < 2; ++n)
            acc[m][n] = __builtin_amdgcn_mfma_f32_16x16x32_f16(af[m][ks], bf[n][ks],
                                                               acc[m][n], 0, 0, 0);
      PR0();
      VM0();
      BAR();
    }
#pragma unroll
    for (int m = 0; m < 4; ++m)
#pragma unroll
      for (int n = 0; n < 2; ++n) {
        const int row = m0s + m * 16 + lk * 4;
        const int col = n0 + wave * 32 + n * 16 + fr;
#pragma unroll
        for (int r = 0; r < 4; ++r)
          Out[(size_t)(row + r) * 1024 + col] = acc[m][n][r];
      }
  }
#undef PSTAGE
}

// ---------------- softmax over full 2048 row, zero t>s; write only what PV reads
__global__ __launch_bounds__(256) void softmax_mask(_Float16* __restrict__ S) {
  const int row = blockIdx.x;
  const int s = row & 2047;
  _Float16* p = S + (size_t)row * 2048;
  const int tid = threadIdx.x;
  uint4 u = ((const uint4*)p)[tid];
  const _Float16* h = (const _Float16*)&u;
  float v[8];
#pragma unroll
  for (int j = 0; j < 8; ++j) v[j] = (float)h[j];
  float mx = v[0];
#pragma unroll
  for (int j = 1; j < 8; ++j) mx = fmaxf(mx, v[j]);
#pragma unroll
  for (int off = 32; off > 0; off >>= 1) mx = fmaxf(mx, __shfl_xor(mx, off));
  __shared__ float red[8];
  const int wave = tid >> 6, lane = tid & 63;
  if (lane == 0) red[wave] = mx;
  __syncthreads();
  mx = fmaxf(fmaxf(red[0], red[1]), fmaxf(red[2], red[3]));
  float se = 0.f;
#pragma unroll
  for (int j = 0; j < 8; ++j) se += __expf(v[j] - mx);
#pragma unroll
  for (int off = 32; off > 0; off >>= 1) se += __shfl_xor(se, off);
  if (lane == 0) red[4 + wave] = se;
  __syncthreads();
  const float inv = 1.f / (red[4] + red[5] + red[6] + red[7]);
  const int lim = (s & ~63) + 64;
  if (tid * 8 < lim) {
    _Float16 o[8];
#pragma unroll
    for (int j = 0; j < 8; ++j) {
      int t = tid * 8 + j;
      o[j] = (_Float16)((t <= s) ? __expf(v[j] - mx) * inv : 0.f);
    }
    ((uint4*)p)[tid] = *(const uint4*)o;
  }
}

extern "C" void kernel_launch(void* const* d_in, const int* in_sizes, int n_in,
                              void* d_out, int out_size, void* d_ws, size_t ws_size,
                              hipStream_t stream) {
  const float* x = (const float*)d_in[0];
  const float* wq = (const float*)d_in[1];
  const float* wv = (const float*)d_in[2];
  float* out = (float*)d_out;
  char* ws = (char*)d_ws;

  const size_t MB = 1024 * 1024;
  const int bc = (ws_size >= 96 * MB) ? 4 : 2;
  const size_t scBytes = (size_t)bc * 2048 * 2048 * 2;
  const long PB = 2048 * 1024;
  const long SB = (long)2048 * 2048;

  _Float16* Sc = (_Float16*)ws;
  _Float16* qh = (_Float16*)(ws + scBytes);
  _Float16* kvh = (_Float16*)(ws + scBytes + 16 * MB);
  _Float16* kvvT = (_Float16*)(ws + scBytes + 32 * MB);
  _Float16* kvT = (_Float16*)(ws + scBytes + 48 * MB);
  _Float16* xh = (_Float16*)ws;                 // transient (inside Sc region)
  _Float16* wqh = (_Float16*)(ws + 16 * MB);
  _Float16* wvh = (_Float16*)(ws + 18 * MB);

  // 1) fp32 -> fp16 (fused)
  cvt3<<<10240, 256, 0, stream>>>(x, wq, wv, xh, wqh, wvh);

  // 2) fused qh = xh@wqh^T, kvh = xh@wvh^T   (lgx=5: mx=s&31; NY*NZ=8 -> G=1)
  gemm8p<_Float16><<<dim3(32, 4, 2), 512, 131072, stream>>>(
      xh, wqh, qh, 1024, 1024, 0, (long)(wvh - wqh), (long)(kvh - qh), 1.0f, 5, 2);

  // 3) B^T materialization
  transpose_f16<<<dim3(32, 16, 4), 256, 0, stream>>>(kvh, kvvT, 1024, 2048);
  transpose_f16<<<dim3(16, 32, 4), 256, 0, stream>>>(kvh, kvT, 2048, 1024);

  // 4) per batch-chunk: scores -> softmax+mask -> balanced causal PV
  for (int b0 = 0; b0 < 4; b0 += bc) {
    gemm8p<_Float16><<<dim3(8, 8, bc), 512, 131072, stream>>>(
        qh + (size_t)b0 * PB, kvvT + (size_t)b0 * PB, Sc,
        1024, 2048, PB, PB, SB, 0.03125f, 3, 3);
    softmax_mask<<<bc * 2048, 256, 0, stream>>>(Sc);
    gemm_pv_bal<<<dim3(16, 8, bc), 256, 0, stream>>>(
        Sc, kvT + (size_t)b0 * PB, out + (size_t)b0 * PB, SB, PB, PB);
  }
}